// Round 1
// baseline (801.265 us; speedup 1.0000x reference)
//
#include <hip/hip_runtime.h>
#include <math.h>

#define B_ 2
#define C_ 64
#define H_ 112
#define W_ 112
#define N_ (H_*W_)        // 12544 src pixels, same count of dst pixels
#define S_ 50
#define G_ 120
#define KNN 3
#define SPLIT 4
#define TILES (N_/64)     // 196 m-tiles of 64
#define TPS (TILES/SPLIT) // 49 tiles per split

// ---------------------------------------------------------------------------
// Kernel 0: detect whether bool masks arrive as 1-byte or int32 elements.
// For int32 0/1 data, every byte at (i % 4 != 0) is zero. For byte bools,
// ~half of them are 1. Deterministic given fixed inputs.
// ---------------------------------------------------------------------------
__global__ void detect_fmt(const unsigned char* __restrict__ m1, int n1,
                           const unsigned char* __restrict__ m2, int n2,
                           int* __restrict__ flags) {
    __shared__ int s1, s2;
    if (threadIdx.x == 0) { s1 = 0; s2 = 0; }
    __syncthreads();
    int a = 0, b = 0;
    for (int i = threadIdx.x; i < n1; i += blockDim.x)
        if ((i & 3) && m1[i]) a = 1;
    for (int i = threadIdx.x; i < n2; i += blockDim.x)
        if ((i & 3) && m2[i]) b = 1;
    if (a) atomicOr(&s1, 1);
    if (b) atomicOr(&s2, 1);
    __syncthreads();
    if (threadIdx.x == 0) { flags[0] = s1; flags[1] = s2; }  // 1 => byte bools
}

// ---------------------------------------------------------------------------
// Kernel 1: normalize dst features (fyn = fy / (||fy||+eps)), save norms,
// and build the additive mask tile (0 valid / -inf masked).
// ---------------------------------------------------------------------------
__global__ void prep(const float* __restrict__ fy,
                     const unsigned char* __restrict__ mask2b,
                     const int* __restrict__ flags,
                     float* __restrict__ fyn, float* __restrict__ nyeps,
                     float* __restrict__ minf) {
    int t = blockIdx.x * blockDim.x + threadIdx.x;   // t = b*N + m
    if (t >= B_ * N_) return;
    int b = t / N_, m = t - b * N_;
    const float* src = fy + (size_t)b * C_ * N_ + m;
    float ss = 0.f;
    #pragma unroll
    for (int c = 0; c < C_; ++c) { float v = src[(size_t)c * N_]; ss = fmaf(v, v, ss); }
    float ny = sqrtf(ss) + 1e-12f;
    float* dst = fyn + (size_t)b * C_ * N_ + m;
    #pragma unroll
    for (int c = 0; c < C_; ++c) dst[(size_t)c * N_] = src[(size_t)c * N_] / ny;
    nyeps[t] = ny;
    bool valid = flags[1] ? (mask2b[t] != 0) : (((const int*)mask2b)[t] != 0);
    minf[t] = valid ? 0.0f : -__builtin_inff();
}

// ---------------------------------------------------------------------------
// Kernel 2: tiled [64 src] x [all m in this split] fp32 dot products with
// running per-thread top-3, then in-block merge across the 16 column-threads.
// grid = (196 n-tiles, 4 splits, 2 batches), block = 256 (16x16, 4x4 micro).
// ---------------------------------------------------------------------------
__global__ __launch_bounds__(256)
void topk_main(const float* __restrict__ fx, const float* __restrict__ fyn,
               const float* __restrict__ minf,
               float* __restrict__ cv, int* __restrict__ ci) {
    __shared__ __align__(16) float fxs[C_][64];
    __shared__ __align__(16) float fys[C_][64];
    __shared__ float msk[64];

    const int tid = threadIdx.x;
    const int tx = tid & 15, ty = tid >> 4;
    const int n0 = blockIdx.x * 64;
    const int split = blockIdx.y;
    const int b = blockIdx.z;

    const float* fxb  = fx  + (size_t)b * C_ * N_;
    const float* fynb = fyn + (size_t)b * C_ * N_;

    // stage the src-feature tile once: fxs[c][n] (c-major)
    for (int i = tid; i < C_ * 16; i += 256) {
        int c = i >> 4, q = i & 15;
        *(float4*)&fxs[c][q * 4] = *(const float4*)(fxb + (size_t)c * N_ + n0 + q * 4);
    }

    float tv[4][3]; int ti[4][3];
    #pragma unroll
    for (int i = 0; i < 4; ++i) {
        tv[i][0] = tv[i][1] = tv[i][2] = -__builtin_inff();
        ti[i][0] = ti[i][1] = ti[i][2] = 0x7fffffff;
    }

    for (int t = split * TPS; t < (split + 1) * TPS; ++t) {
        const int m0 = t * 64;
        __syncthreads();   // previous compute done before overwriting fys
        for (int i = tid; i < C_ * 16; i += 256) {
            int c = i >> 4, q = i & 15;
            *(float4*)&fys[c][q * 4] = *(const float4*)(fynb + (size_t)c * N_ + m0 + q * 4);
        }
        if (tid < 64) msk[tid] = minf[(size_t)b * N_ + m0 + tid];
        __syncthreads();

        float acc[4][4];
        #pragma unroll
        for (int i = 0; i < 4; ++i)
            #pragma unroll
            for (int j = 0; j < 4; ++j) acc[i][j] = 0.f;

        #pragma unroll 8
        for (int c = 0; c < C_; ++c) {
            float4 a  = *(const float4*)&fxs[c][ty * 4];
            float4 bv = *(const float4*)&fys[c][tx * 4];
            float av[4] = {a.x, a.y, a.z, a.w};
            float bb[4] = {bv.x, bv.y, bv.z, bv.w};
            #pragma unroll
            for (int i = 0; i < 4; ++i)
                #pragma unroll
                for (int j = 0; j < 4; ++j)
                    acc[i][j] = fmaf(av[i], bb[j], acc[i][j]);
        }

        // top-3 update (scan ascending m; strict '>' keeps earliest index on ties)
        #pragma unroll
        for (int j = 0; j < 4; ++j) {
            float mm = msk[tx * 4 + j];
            int idx = m0 + tx * 4 + j;
            #pragma unroll
            for (int i = 0; i < 4; ++i) {
                float s = acc[i][j] + mm;
                if (s > tv[i][2]) {
                    if (s > tv[i][1]) {
                        tv[i][2] = tv[i][1]; ti[i][2] = ti[i][1];
                        if (s > tv[i][0]) {
                            tv[i][1] = tv[i][0]; ti[i][1] = ti[i][0];
                            tv[i][0] = s; ti[i][0] = idx;
                        } else { tv[i][1] = s; ti[i][1] = idx; }
                    } else { tv[i][2] = s; ti[i][2] = idx; }
                }
            }
        }
    }

    // merge the 16 column-threads' top-3 lists per row (reuse LDS)
    __syncthreads();
    float* cvals = &fxs[0][0];       // 64 rows * 48 candidates
    int*   cidx  = (int*)&fys[0][0];
    #pragma unroll
    for (int i = 0; i < 4; ++i) {
        int row = ty * 4 + i;
        #pragma unroll
        for (int k = 0; k < 3; ++k) {
            cvals[row * 48 + tx * 3 + k] = tv[i][k];
            cidx [row * 48 + tx * 3 + k] = ti[i][k];
        }
    }
    __syncthreads();
    if (tid < 64) {
        const int row = tid;
        float bv0 = -__builtin_inff(), bv1 = bv0, bv2 = bv0;
        int bi0 = 0x7fffffff, bi1 = bi0, bi2 = bi0;
        for (int k = 0; k < 48; ++k) {
            float v = cvals[row * 48 + k]; int id = cidx[row * 48 + k];
            if ((v > bv2) || (v == bv2 && id < bi2)) {
                if ((v > bv1) || (v == bv1 && id < bi1)) {
                    bv2 = bv1; bi2 = bi1;
                    if ((v > bv0) || (v == bv0 && id < bi0)) {
                        bv1 = bv0; bi1 = bi0; bv0 = v; bi0 = id;
                    } else { bv1 = v; bi1 = id; }
                } else { bv2 = v; bi2 = id; }
            }
        }
        size_t base = (((size_t)b * N_ + n0 + row) * SPLIT + split) * 3;
        cv[base] = bv0; cv[base + 1] = bv1; cv[base + 2] = bv2;
        ci[base] = bi0; ci[base + 1] = bi1; ci[base + 2] = bi2;
    }
}

// ---------------------------------------------------------------------------
// Kernel 3: merge the 4 splits' candidates, compute weighted-average coords.
// w_k = sim_unnorm_k * (||fy_idx||+eps) == raw dot fx.fy at the match.
// ---------------------------------------------------------------------------
__global__ void merge_pred(const float* __restrict__ cv, const int* __restrict__ ci,
                           const float* __restrict__ nyeps,
                           const unsigned char* __restrict__ mask1b,
                           const int* __restrict__ flags,
                           float* __restrict__ out) {
    int t = blockIdx.x * blockDim.x + threadIdx.x;   // t = b*N + n
    if (t >= B_ * N_) return;
    int b = t / N_;
    float bv0 = -__builtin_inff(), bv1 = bv0, bv2 = bv0;
    int bi0 = 0x7fffffff, bi1 = bi0, bi2 = bi0;
    size_t base = (size_t)t * SPLIT * 3;
    #pragma unroll
    for (int k = 0; k < SPLIT * 3; ++k) {
        float v = cv[base + k]; int id = ci[base + k];
        if ((v > bv2) || (v == bv2 && id < bi2)) {
            if ((v > bv1) || (v == bv1 && id < bi1)) {
                bv2 = bv1; bi2 = bi1;
                if ((v > bv0) || (v == bv0 && id < bi0)) {
                    bv1 = bv0; bi1 = bi0; bv0 = v; bi0 = id;
                } else { bv1 = v; bi1 = id; }
            } else { bv2 = v; bi2 = id; }
        }
    }
    float w0 = bv0 * nyeps[(size_t)b * N_ + bi0];
    float w1 = bv1 * nyeps[(size_t)b * N_ + bi1];
    float w2 = bv2 * nyeps[(size_t)b * N_ + bi2];
    float h0 = (float)(bi0 / W_), h1 = (float)(bi1 / W_), h2 = (float)(bi2 / W_);
    float q0 = (float)(bi0 % W_), q1 = (float)(bi1 % W_), q2 = (float)(bi2 % W_);
    float den = w0 + w1 + w2;
    float ph = (h0 * w0 + h1 * w1 + h2 * w2) / den;
    float pw = (q0 * w0 + q1 * w1 + q2 * w2) / den;
    bool m1 = flags[0] ? (mask1b[t] != 0) : (((const int*)mask1b)[t] != 0);
    out[2 * t]     = m1 ? ph : -1.0f;
    out[2 * t + 1] = m1 ? pw : -1.0f;
}

// ---------------------------------------------------------------------------
// Kernel 4: slic gather — round/clip src pixel coords, gather pred_corr, /112.
// ---------------------------------------------------------------------------
__global__ void slic_gather(const float* __restrict__ spg,
                            const float* __restrict__ pred,
                            float* __restrict__ outg) {
    int t = blockIdx.x * blockDim.x + threadIdx.x;  // t = b*S*G + s*G + g
    if (t >= B_ * S_ * G_) return;
    int b = t / (S_ * G_);
    float vh = spg[2 * t], vw = spg[2 * t + 1];
    int ph = (int)rintf(vh * (float)H_);            // round-half-even == jnp.round
    int pw = (int)rintf(vw * (float)H_);
    ph = ph < 0 ? 0 : (ph > H_ - 1 ? H_ - 1 : ph);
    pw = pw < 0 ? 0 : (pw > H_ - 1 ? H_ - 1 : pw);
    int lin = ph * W_ + pw;
    float oh = pred[((size_t)b * N_ + lin) * 2];
    float ow = pred[((size_t)b * N_ + lin) * 2 + 1];
    outg[2 * t]     = oh / (float)H_;               // norm_h = slic.shape[1] = 112
    outg[2 * t + 1] = ow / (float)H_;
}

extern "C" void kernel_launch(void* const* d_in, const int* in_sizes, int n_in,
                              void* d_out, int out_size, void* d_ws, size_t ws_size,
                              hipStream_t stream) {
    const float* img1 = (const float*)d_in[0];   // src features [B,C,H,W]
    const float* img2 = (const float*)d_in[1];   // dst features [B,C,H,W]
    const void*  mask1 = d_in[2];
    const void*  mask2 = d_in[3];
    const float* spg = (const float*)d_in[4];    // [B,S,G,2]
    // d_in[5] (slic) only contributes its shape (norm_h = 112); never read.
    float* out = (float*)d_out;

    char* ws = (char*)d_ws;
    int*   flags = (int*)ws;                                   // 2 ints
    float* fyn   = (float*)(ws + 256);                         // B*C*N
    float* nyeps = (float*)(ws + 256 + (size_t)B_ * C_ * N_ * 4);
    float* minf  = nyeps + (size_t)B_ * N_;
    float* cv    = minf + (size_t)B_ * N_;                     // B*N*SPLIT*3
    int*   ci    = (int*)(cv + (size_t)B_ * N_ * SPLIT * 3);

    detect_fmt<<<1, 256, 0, stream>>>((const unsigned char*)mask1, B_ * N_,
                                      (const unsigned char*)mask2, B_ * N_, flags);
    prep<<<(B_ * N_ + 255) / 256, 256, 0, stream>>>(
        img2, (const unsigned char*)mask2, flags, fyn, nyeps, minf);
    dim3 g(TILES, SPLIT, B_);
    topk_main<<<g, 256, 0, stream>>>(img1, fyn, minf, cv, ci);
    merge_pred<<<(B_ * N_ + 255) / 256, 256, 0, stream>>>(
        cv, ci, nyeps, (const unsigned char*)mask1, flags, out);
    slic_gather<<<(B_ * S_ * G_ + 255) / 256, 256, 0, stream>>>(
        spg, out, out + (size_t)B_ * N_ * 2);
}

// Round 3
// 581.356 us; speedup vs baseline: 1.3783x; 1.3783x over previous
//
#include <hip/hip_runtime.h>
#include <math.h>

typedef _Float16 f16;
typedef f16 f16x8 __attribute__((ext_vector_type(8)));
typedef float f32x16 __attribute__((ext_vector_type(16)));
typedef unsigned short u16;

#define B_ 2
#define C_ 64
#define KS 5             // K-steps of 16 (64 feats + mask ch + zero pad = 80)
#define H_ 112
#define W_ 112
#define N_ 12544
#define S_ 50
#define G_ 120
#define MT 392           // m-tiles of 32
#define NT 392           // n-subtiles of 32
#define SPLIT 8
#define TPS (MT/SPLIT)   // 49 m-tiles per split
#define GROUP 4
#define NG ((TPS + GROUP - 1)/GROUP)   // 13 groups (12 full + 1 tail)
#define LCAP 8           // per-lane top-8
#define CPR (SPLIT*2*LCAP) // 128 candidates per row

union U16B { uint4 u; f16x8 h; f16 e[8]; };

__device__ __forceinline__ void glds16(const uint4* g, uint4* l) {
    __builtin_amdgcn_global_load_lds(
        (const __attribute__((address_space(1))) unsigned int*)g,
        (__attribute__((address_space(3))) unsigned int*)l, 16, 0, 0);
}

// ---------------------------------------------------------------------------
// Kernel 0: detect whether bool masks arrive as 1-byte or int32 elements.
// ---------------------------------------------------------------------------
__global__ void detect_fmt(const unsigned char* __restrict__ m1, int n1,
                           const unsigned char* __restrict__ m2, int n2,
                           int* __restrict__ flags) {
    __shared__ int s1, s2;
    if (threadIdx.x == 0) { s1 = 0; s2 = 0; }
    __syncthreads();
    int a = 0, b = 0;
    for (int i = threadIdx.x; i < n1; i += blockDim.x)
        if ((i & 3) && m1[i]) a = 1;
    for (int i = threadIdx.x; i < n2; i += blockDim.x)
        if ((i & 3) && m2[i]) b = 1;
    if (a) atomicOr(&s1, 1);
    if (b) atomicOr(&s2, 1);
    __syncthreads();
    if (threadIdx.x == 0) { flags[0] = s1; flags[1] = s2; }  // 1 => byte bools
}

// ---------------------------------------------------------------------------
// Kernel 1a: dst features — fp32 fynT rows (bitwise same math as round 1),
// fp16 frag-ordered fynq (mask channel at k=64: 0 valid / -1e4 masked),
// nyeps, minf.
// fynq layout: [b][tile(392)][ks(5)][lane(64)][8 f16]; lane=hi*32+row,
// element i = fyn[tile*32+row][16*ks + 8*hi + i]  (A-frag order; any
// consistent k-permutation cancels between A and B).
// ---------------------------------------------------------------------------
__global__ void prepY(const float* __restrict__ fy,
                      const unsigned char* __restrict__ mask2b,
                      const int* __restrict__ flags,
                      float* __restrict__ fynT, f16* __restrict__ fynq,
                      float* __restrict__ nyeps, float* __restrict__ minf) {
    int t = blockIdx.x * blockDim.x + threadIdx.x;   // t = b*N + m
    if (t >= B_ * N_) return;
    int b = t / N_, m = t - b * N_;
    const float* src = fy + (size_t)b * C_ * N_ + m;
    float v[64];
    float ss = 0.f;
    #pragma unroll
    for (int c = 0; c < C_; ++c) { v[c] = src[(size_t)c * N_]; ss = fmaf(v[c], v[c], ss); }
    float ny = sqrtf(ss) + 1e-12f;
    nyeps[t] = ny;
    bool valid = flags[1] ? (mask2b[t] != 0) : (((const int*)mask2b)[t] != 0);
    minf[t] = valid ? 0.0f : -__builtin_inff();
    float mval = valid ? 0.0f : -1.0e4f;

    float* dT = fynT + (size_t)t * C_;
    #pragma unroll
    for (int c = 0; c < C_; ++c) dT[c] = v[c] / ny;   // same arithmetic as round 1

    int tile = m >> 5, r = m & 31;
    uint4* q4 = (uint4*)fynq;
    size_t cb = (size_t)(b * MT + tile) * KS * 64;
    #pragma unroll
    for (int ks = 0; ks < KS; ++ks) {
        #pragma unroll
        for (int hi = 0; hi < 2; ++hi) {
            U16B tmp;
            #pragma unroll
            for (int i = 0; i < 8; ++i) {
                int k = 16 * ks + 8 * hi + i;
                float val = (k < 64) ? (v[k] / ny) : ((k == 64) ? mval : 0.0f);
                tmp.e[i] = (f16)val;
            }
            q4[cb + (size_t)ks * 64 + hi * 32 + r] = tmp.u;
        }
    }
}

// ---------------------------------------------------------------------------
// Kernel 1b: src features — fp16 frag-ordered fxq (B-frag order; channel
// k=64 is 1.0 so the mask channel flows through).
// ---------------------------------------------------------------------------
__global__ void prepX(const float* __restrict__ fx, f16* __restrict__ fxq) {
    int t = blockIdx.x * blockDim.x + threadIdx.x;   // t = b*N + n
    if (t >= B_ * N_) return;
    int b = t / N_, n = t - b * N_;
    const float* src = fx + (size_t)b * C_ * N_ + n;
    float v[64];
    #pragma unroll
    for (int c = 0; c < C_; ++c) v[c] = src[(size_t)c * N_];

    int tile = n >> 5, r = n & 31;
    uint4* q4 = (uint4*)fxq;
    size_t cb = (size_t)(b * NT + tile) * KS * 64;
    #pragma unroll
    for (int ks = 0; ks < KS; ++ks) {
        #pragma unroll
        for (int hi = 0; hi < 2; ++hi) {
            U16B tmp;
            #pragma unroll
            for (int i = 0; i < 8; ++i) {
                int k = 16 * ks + 8 * hi + i;
                float val = (k < 64) ? v[k] : ((k == 64) ? 1.0f : 0.0f);
                tmp.e[i] = (f16)val;
            }
            q4[cb + (size_t)ks * 64 + hi * 32 + r] = tmp.u;
        }
    }
}

// ---------------------------------------------------------------------------
// Kernel 2: MFMA candidate pass. D[m][n] = fyn_f16[m][k]*fx_f16[k][n] via
// mfma_f32_32x32x16_f16 (swapped operands: m-axis spreads over regs+hi,
// n = lane&31). Each lane keeps top-8 (value,index) of its disjoint
// 16-rows-per-tile m-subset; writes 8 indices per (n, split, hi) to cands.
// Block: 4 waves x 2 n-subtiles = 256 n. grid = (49, 8 splits, 2 batches).
// LDS double-buffered m-tile groups staged via global_load_lds.
// ---------------------------------------------------------------------------
__global__ __launch_bounds__(256, 2)
void stage1(const f16* __restrict__ fxq, const f16* __restrict__ fynq,
            u16* __restrict__ cands) {
    __shared__ uint4 lds[2][GROUP * KS * 64];   // 2 x 20 KiB

    const int tid = threadIdx.x;
    const int lane = tid & 63, w = tid >> 6;
    const int lo = lane & 31, hi = lane >> 5;
    const int nb = blockIdx.x;
    const int split = blockIdx.y;
    const int b = blockIdx.z;
    const int tbase = split * TPS;

    const uint4* fxq4 = (const uint4*)fxq;
    const uint4* fyq4 = (const uint4*)fynq;

    // resident B-fragments: fx for this wave's 2 n-subtiles
    f16x8 bfr[2][KS];
    #pragma unroll
    for (int s = 0; s < 2; ++s) {
        int nt = nb * 8 + w * 2 + s;
        #pragma unroll
        for (int ks = 0; ks < KS; ++ks) {
            U16B u; u.u = fxq4[((size_t)(b * NT + nt) * KS + ks) * 64 + lane];
            bfr[s][ks] = u.h;
        }
    }

    float lv[2][LCAP]; int li[2][LCAP];
    #pragma unroll
    for (int s = 0; s < 2; ++s)
        #pragma unroll
        for (int k = 0; k < LCAP; ++k) { lv[s][k] = -__builtin_inff(); li[s][k] = 65535; }

    // prologue: stage group 0
    {
        int cnt = (TPS < GROUP) ? TPS : GROUP;
        for (int c = w; c < cnt * KS; c += 4)
            glds16(fyq4 + (((size_t)(b * MT + tbase + c / KS) * KS + (c % KS)) * 64 + lane),
                   &lds[0][c * 64]);
    }
    __syncthreads();   // drains vmcnt(0) before first compute

    for (int g = 0; g < NG; ++g) {
        const int cur = g & 1;
        // issue next group's stage into the other buffer (overlaps compute)
        if (g + 1 < NG) {
            int t0n = tbase + (g + 1) * GROUP;
            int cntn = TPS - (g + 1) * GROUP; if (cntn > GROUP) cntn = GROUP;
            for (int c = w; c < cntn * KS; c += 4)
                glds16(fyq4 + (((size_t)(b * MT + t0n + c / KS) * KS + (c % KS)) * 64 + lane),
                       &lds[1 - cur][c * 64]);
        }
        // compute this group's tiles
        int t0 = tbase + g * GROUP;
        int cnt = TPS - g * GROUP; if (cnt > GROUP) cnt = GROUP;
        for (int tl = 0; tl < cnt; ++tl) {
            const int m0 = (t0 + tl) * 32;
            f16x8 a[KS];
            #pragma unroll
            for (int ks = 0; ks < KS; ++ks) {
                U16B u; u.u = lds[cur][(tl * KS + ks) * 64 + lane];
                a[ks] = u.h;
            }
            #pragma unroll
            for (int s = 0; s < 2; ++s) {
                f32x16 acc = {};
                #pragma unroll
                for (int ks = 0; ks < KS; ++ks)
                    acc = __builtin_amdgcn_mfma_f32_32x32x16_f16(a[ks], bfr[s][ks], acc, 0, 0, 0);
                // tile-max filter then rare sorted-insert into per-lane top-8
                float tmax = acc[0];
                #pragma unroll
                for (int r = 1; r < 16; ++r) tmax = fmaxf(tmax, acc[r]);
                if (tmax > lv[s][LCAP - 1]) {
                    #pragma unroll
                    for (int r = 0; r < 16; ++r) {
                        float v = acc[r];
                        if (v > lv[s][LCAP - 1]) {
                            int idx = m0 + ((r & 3) + 8 * (r >> 2) + 4 * hi);
                            #pragma unroll
                            for (int j = LCAP - 1; j >= 1; --j) {
                                bool gj  = v > lv[s][j];
                                bool gj1 = v > lv[s][j - 1];
                                float nv = gj ? (gj1 ? lv[s][j - 1] : v) : lv[s][j];
                                int   ni = gj ? (gj1 ? li[s][j - 1] : idx) : li[s][j];
                                lv[s][j] = nv; li[s][j] = ni;
                            }
                            if (v > lv[s][0]) { lv[s][0] = v; li[s][0] = idx; }
                        }
                    }
                }
            }
        }
        __syncthreads();   // drains the prefetch vmcnt before buffer swap
    }

    // write candidate indices: cands[b][n][split][hi][8]
    #pragma unroll
    for (int s = 0; s < 2; ++s) {
        int nt = nb * 8 + w * 2 + s;
        int n = nt * 32 + lo;
        size_t base = (((size_t)b * N_ + n) * SPLIT + split) * (2 * LCAP) + hi * LCAP;
        #pragma unroll
        for (int k = 0; k < LCAP; ++k) cands[base + k] = (u16)li[s][k];
    }
}

// ---------------------------------------------------------------------------
// Kernel 3: exact rescore. One wave per src row; 2 candidates per lane.
// Dot = sequential fmaf over c (bit-identical to round-1 arithmetic).
// Rank = dot + minf[m] (-inf re-mask); weight = dot * nyeps[m].
// 3-round butterfly argmax (tiebreak: lower index) -> pred coords.
// ---------------------------------------------------------------------------
__global__ __launch_bounds__(256)
void rescore(const u16* __restrict__ cands, const float* __restrict__ fx,
             const float* __restrict__ fynT, const float* __restrict__ nyeps,
             const float* __restrict__ minf,
             const unsigned char* __restrict__ mask1b,
             const int* __restrict__ flags, float* __restrict__ out) {
    int gw = blockIdx.x * 4 + (threadIdx.x >> 6);    // row = b*N + n
    int lane = threadIdx.x & 63;
    if (gw >= B_ * N_) return;
    int b = gw / N_, n = gw - b * N_;

    const u16* cr = cands + (size_t)gw * CPR;
    int idx[2]; idx[0] = cr[2 * lane]; idx[1] = cr[2 * lane + 1];

    const float* fxb = fx + (size_t)b * C_ * N_ + n;   // fx[b][c][n], stride N_
    float rnk[2], wgt[2];
    #pragma unroll
    for (int k = 0; k < 2; ++k) {
        bool valid = idx[k] < N_;
        int m = valid ? idx[k] : 0;
        const float* fr = fynT + ((size_t)b * N_ + m) * C_;
        float a = 0.f;
        #pragma unroll 4
        for (int c = 0; c < C_; c += 4) {
            a = fmaf(fxb[(size_t)(c + 0) * N_], fr[c + 0], a);
            a = fmaf(fxb[(size_t)(c + 1) * N_], fr[c + 1], a);
            a = fmaf(fxb[(size_t)(c + 2) * N_], fr[c + 2], a);
            a = fmaf(fxb[(size_t)(c + 3) * N_], fr[c + 3], a);
        }
        rnk[k] = valid ? (a + minf[(size_t)b * N_ + m]) : -__builtin_inff();
        wgt[k] = a * nyeps[(size_t)b * N_ + m];
        idx[k] = valid ? idx[k] : 0x7fffffff;
    }

    int wi[3]; float ww[3];
    #pragma unroll
    for (int r = 0; r < 3; ++r) {
        bool t01 = (rnk[1] > rnk[0]) || (rnk[1] == rnk[0] && idx[1] < idx[0]);
        float cv = t01 ? rnk[1] : rnk[0];
        int   ci = t01 ? idx[1] : idx[0];
        float cw = t01 ? wgt[1] : wgt[0];
        #pragma unroll
        for (int off = 32; off >= 1; off >>= 1) {
            float ov = __shfl_xor(cv, off);
            int   oi = __shfl_xor(ci, off);
            float ow = __shfl_xor(cw, off);
            bool take = (ov > cv) || (ov == cv && oi < ci);
            cv = take ? ov : cv; ci = take ? oi : ci; cw = take ? ow : cw;
        }
        wi[r] = ci; ww[r] = cw;
        if (idx[0] == ci) rnk[0] = -__builtin_inff();
        if (idx[1] == ci) rnk[1] = -__builtin_inff();
    }

    if (lane == 0) {
        float w0 = ww[0], w1 = ww[1], w2 = ww[2];
        float h0 = (float)(wi[0] / W_), h1 = (float)(wi[1] / W_), h2 = (float)(wi[2] / W_);
        float q0 = (float)(wi[0] % W_), q1 = (float)(wi[1] % W_), q2 = (float)(wi[2] % W_);
        float den = w0 + w1 + w2;
        float ph = (h0 * w0 + h1 * w1 + h2 * w2) / den;
        float pw = (q0 * w0 + q1 * w1 + q2 * w2) / den;
        bool m1 = flags[0] ? (mask1b[gw] != 0) : (((const int*)mask1b)[gw] != 0);
        out[2 * gw]     = m1 ? ph : -1.0f;
        out[2 * gw + 1] = m1 ? pw : -1.0f;
    }
}

// ---------------------------------------------------------------------------
// Kernel 4: slic gather.
// ---------------------------------------------------------------------------
__global__ void slic_gather(const float* __restrict__ spg,
                            const float* __restrict__ pred,
                            float* __restrict__ outg) {
    int t = blockIdx.x * blockDim.x + threadIdx.x;
    if (t >= B_ * S_ * G_) return;
    int b = t / (S_ * G_);
    float vh = spg[2 * t], vw = spg[2 * t + 1];
    int ph = (int)rintf(vh * (float)H_);
    int pw = (int)rintf(vw * (float)H_);
    ph = ph < 0 ? 0 : (ph > H_ - 1 ? H_ - 1 : ph);
    pw = pw < 0 ? 0 : (pw > H_ - 1 ? H_ - 1 : pw);
    int lin = ph * W_ + pw;
    outg[2 * t]     = pred[((size_t)b * N_ + lin) * 2]     / (float)H_;
    outg[2 * t + 1] = pred[((size_t)b * N_ + lin) * 2 + 1] / (float)H_;
}

extern "C" void kernel_launch(void* const* d_in, const int* in_sizes, int n_in,
                              void* d_out, int out_size, void* d_ws, size_t ws_size,
                              hipStream_t stream) {
    const float* img1 = (const float*)d_in[0];
    const float* img2 = (const float*)d_in[1];
    const void*  mask1 = d_in[2];
    const void*  mask2 = d_in[3];
    const float* spg = (const float*)d_in[4];
    float* out = (float*)d_out;

    char* ws = (char*)d_ws;
    size_t off = 0;
    int*   flags = (int*)(ws + off);            off += 256;
    float* fynT  = (float*)(ws + off);          off += (size_t)B_ * N_ * C_ * 4;       // 6.42 MB
    f16*   fxq   = (f16*)(ws + off);            off += (size_t)B_ * NT * KS * 64 * 16; // 4.01 MB
    f16*   fynq  = (f16*)(ws + off);            off += (size_t)B_ * MT * KS * 64 * 16; // 4.01 MB
    float* nyeps = (float*)(ws + off);          off += (size_t)B_ * N_ * 4;
    float* minf  = (float*)(ws + off);          off += (size_t)B_ * N_ * 4;
    u16*   cands = (u16*)(ws + off);            off += (size_t)B_ * N_ * CPR * 2;      // 6.42 MB

    detect_fmt<<<1, 256, 0, stream>>>((const unsigned char*)mask1, B_ * N_,
                                      (const unsigned char*)mask2, B_ * N_, flags);
    prepY<<<(B_ * N_) / 256, 256, 0, stream>>>(
        img2, (const unsigned char*)mask2, flags, fynT, fynq, nyeps, minf);
    prepX<<<(B_ * N_) / 256, 256, 0, stream>>>(img1, fxq);

    dim3 g1(49, SPLIT, B_);
    stage1<<<g1, 256, 0, stream>>>(fxq, fynq, cands);

    rescore<<<(B_ * N_) / 4, 256, 0, stream>>>(   // one wave per row: 6272 blocks
        cands, img1, fynT, nyeps, minf, (const unsigned char*)mask1, flags, out);

    slic_gather<<<(B_ * S_ * G_ + 255) / 256, 256, 0, stream>>>(
        spg, out, out + (size_t)B_ * N_ * 2);
}

// Round 4
// 379.476 us; speedup vs baseline: 2.1115x; 1.5320x over previous
//
#include <hip/hip_runtime.h>
#include <math.h>

typedef _Float16 f16;
typedef f16 f16x8 __attribute__((ext_vector_type(8)));
typedef float f32x16 __attribute__((ext_vector_type(16)));
typedef unsigned short u16;

#define B_ 2
#define C_ 64
#define KS 5             // K-steps of 16 (64 feats + mask ch + zero pad = 80)
#define H_ 112
#define W_ 112
#define N_ 12544
#define S_ 50
#define G_ 120
#define MT 392           // m-tiles of 32
#define NT 392           // n-subtiles of 32
#define SPLIT 8
#define TPS (MT/SPLIT)   // 49 m-tiles per split
#define GROUP 4
#define NG ((TPS + GROUP - 1)/GROUP)   // 13 groups
#define LCAP 4           // per-lane top-4 (exact rank <=3 + 1 noise-margin slot)
#define CPR (SPLIT*2*LCAP) // 64 candidates per row -> 1 per lane in rescore

#define NEGINF (-__builtin_inff())

union U16B { uint4 u; f16x8 h; f16 e[8]; };

__device__ __forceinline__ void glds16(const uint4* g, uint4* l) {
    __builtin_amdgcn_global_load_lds(
        (const __attribute__((address_space(1))) unsigned int*)g,
        (__attribute__((address_space(3))) unsigned int*)l, 16, 0, 0);
}

// 4-deep sorted insert (desc). Caller guarantees v > lv[3]. Strict '>' keeps
// earlier-inserted (lower m) ahead on ties, matching top_k tie-break.
__device__ __forceinline__ void ins4(float* lv, int* li, float v, int idx) {
    bool g2 = v > lv[2], g1 = v > lv[1], g0 = v > lv[0];
    lv[3] = g2 ? lv[2] : v;                 li[3] = g2 ? li[2] : idx;
    lv[2] = g2 ? (g1 ? lv[1] : v) : lv[2];  li[2] = g2 ? (g1 ? li[1] : idx) : li[2];
    lv[1] = g1 ? (g0 ? lv[0] : v) : lv[1];  li[1] = g1 ? (g0 ? li[0] : idx) : li[1];
    lv[0] = g0 ? v : lv[0];                 li[0] = g0 ? idx : li[0];
}

// ---------------------------------------------------------------------------
// Kernel 0: detect whether bool masks arrive as 1-byte or int32 elements.
// ---------------------------------------------------------------------------
__global__ void detect_fmt(const unsigned char* __restrict__ m1, int n1,
                           const unsigned char* __restrict__ m2, int n2,
                           int* __restrict__ flags) {
    __shared__ int s1, s2;
    if (threadIdx.x == 0) { s1 = 0; s2 = 0; }
    __syncthreads();
    int a = 0, b = 0;
    for (int i = threadIdx.x; i < n1; i += blockDim.x)
        if ((i & 3) && m1[i]) a = 1;
    for (int i = threadIdx.x; i < n2; i += blockDim.x)
        if ((i & 3) && m2[i]) b = 1;
    if (a) atomicOr(&s1, 1);
    if (b) atomicOr(&s2, 1);
    __syncthreads();
    if (threadIdx.x == 0) { flags[0] = s1; flags[1] = s2; }  // 1 => byte bools
}

// ---------------------------------------------------------------------------
// Kernel 1a: dst features — fp32 fynT rows (bitwise same math as round 1),
// fp16 frag-ordered fynq (mask channel at k=64: 0 valid / -1e4 masked),
// nyeps, minf.
// ---------------------------------------------------------------------------
__global__ void prepY(const float* __restrict__ fy,
                      const unsigned char* __restrict__ mask2b,
                      const int* __restrict__ flags,
                      float* __restrict__ fynT, f16* __restrict__ fynq,
                      float* __restrict__ nyeps, float* __restrict__ minf) {
    int t = blockIdx.x * blockDim.x + threadIdx.x;   // t = b*N + m
    if (t >= B_ * N_) return;
    int b = t / N_, m = t - b * N_;
    const float* src = fy + (size_t)b * C_ * N_ + m;
    float v[64];
    float ss = 0.f;
    #pragma unroll
    for (int c = 0; c < C_; ++c) { v[c] = src[(size_t)c * N_]; ss = fmaf(v[c], v[c], ss); }
    float ny = sqrtf(ss) + 1e-12f;
    nyeps[t] = ny;
    bool valid = flags[1] ? (mask2b[t] != 0) : (((const int*)mask2b)[t] != 0);
    minf[t] = valid ? 0.0f : NEGINF;
    float mval = valid ? 0.0f : -1.0e4f;

    float* dT = fynT + (size_t)t * C_;
    #pragma unroll
    for (int c = 0; c < C_; ++c) dT[c] = v[c] / ny;   // same arithmetic as round 1

    int tile = m >> 5, r = m & 31;
    uint4* q4 = (uint4*)fynq;
    size_t cb = (size_t)(b * MT + tile) * KS * 64;
    #pragma unroll
    for (int ks = 0; ks < KS; ++ks) {
        #pragma unroll
        for (int hi = 0; hi < 2; ++hi) {
            U16B tmp;
            #pragma unroll
            for (int i = 0; i < 8; ++i) {
                int k = 16 * ks + 8 * hi + i;
                float val = (k < 64) ? (v[k] / ny) : ((k == 64) ? mval : 0.0f);
                tmp.e[i] = (f16)val;
            }
            q4[cb + (size_t)ks * 64 + hi * 32 + r] = tmp.u;
        }
    }
}

// ---------------------------------------------------------------------------
// Kernel 1b: src features — fp16 frag-ordered fxq (k=64 channel = 1.0).
// ---------------------------------------------------------------------------
__global__ void prepX(const float* __restrict__ fx, f16* __restrict__ fxq) {
    int t = blockIdx.x * blockDim.x + threadIdx.x;   // t = b*N + n
    if (t >= B_ * N_) return;
    int b = t / N_, n = t - b * N_;
    const float* src = fx + (size_t)b * C_ * N_ + n;
    float v[64];
    #pragma unroll
    for (int c = 0; c < C_; ++c) v[c] = src[(size_t)c * N_];

    int tile = n >> 5, r = n & 31;
    uint4* q4 = (uint4*)fxq;
    size_t cb = (size_t)(b * NT + tile) * KS * 64;
    #pragma unroll
    for (int ks = 0; ks < KS; ++ks) {
        #pragma unroll
        for (int hi = 0; hi < 2; ++hi) {
            U16B tmp;
            #pragma unroll
            for (int i = 0; i < 8; ++i) {
                int k = 16 * ks + 8 * hi + i;
                float val = (k < 64) ? v[k] : ((k == 64) ? 1.0f : 0.0f);
                tmp.e[i] = (f16)val;
            }
            q4[cb + (size_t)ks * 64 + hi * 32 + r] = tmp.u;
        }
    }
}

// ---------------------------------------------------------------------------
// Kernel 2: MFMA candidate pass. Per (m-tile, n-subtile) event: 5 MFMAs,
// then fused single-pass top-3-of-16 extraction (cell-top-3 policy) with
// guarded inserts into a per-lane sorted top-4. Guarantee: any row-top-3
// value has exact rank <=3 within its lane's cell-filtered stream; LCAP=4
// leaves one slot of f16-noise margin; all-3-in-one-cell is captured by
// the 3-level extraction.
// ---------------------------------------------------------------------------
__global__ __launch_bounds__(256, 2)
void stage1(const f16* __restrict__ fxq, const f16* __restrict__ fynq,
            u16* __restrict__ cands) {
    __shared__ uint4 lds[2][GROUP * KS * 64];   // 2 x 20 KiB

    const int tid = threadIdx.x;
    const int lane = tid & 63, w = tid >> 6;
    const int lo = lane & 31, hi = lane >> 5;
    const int nb = blockIdx.x;
    const int split = blockIdx.y;
    const int b = blockIdx.z;
    const int tbase = split * TPS;

    const uint4* fxq4 = (const uint4*)fxq;
    const uint4* fyq4 = (const uint4*)fynq;

    // resident B-fragments: fx for this wave's 2 n-subtiles
    f16x8 bfr[2][KS];
    #pragma unroll
    for (int s = 0; s < 2; ++s) {
        int nt = nb * 8 + w * 2 + s;
        #pragma unroll
        for (int ks = 0; ks < KS; ++ks) {
            U16B u; u.u = fxq4[((size_t)(b * NT + nt) * KS + ks) * 64 + lane];
            bfr[s][ks] = u.h;
        }
    }

    float lv[2][LCAP]; int li[2][LCAP];
    #pragma unroll
    for (int s = 0; s < 2; ++s)
        #pragma unroll
        for (int k = 0; k < LCAP; ++k) { lv[s][k] = NEGINF; li[s][k] = 65535; }

    // prologue: stage group 0
    {
        int cnt = (TPS < GROUP) ? TPS : GROUP;
        for (int c = w; c < cnt * KS; c += 4)
            glds16(fyq4 + (((size_t)(b * MT + tbase + c / KS) * KS + (c % KS)) * 64 + lane),
                   &lds[0][c * 64]);
    }
    __syncthreads();

    for (int g = 0; g < NG; ++g) {
        const int cur = g & 1;
        if (g + 1 < NG) {
            int t0n = tbase + (g + 1) * GROUP;
            int cntn = TPS - (g + 1) * GROUP; if (cntn > GROUP) cntn = GROUP;
            for (int c = w; c < cntn * KS; c += 4)
                glds16(fyq4 + (((size_t)(b * MT + t0n + c / KS) * KS + (c % KS)) * 64 + lane),
                       &lds[1 - cur][c * 64]);
        }
        int t0 = tbase + g * GROUP;
        int cnt = TPS - g * GROUP; if (cnt > GROUP) cnt = GROUP;
        for (int tl = 0; tl < cnt; ++tl) {
            const int m0 = (t0 + tl) * 32;
            f16x8 a[KS];
            #pragma unroll
            for (int ks = 0; ks < KS; ++ks) {
                U16B u; u.u = lds[cur][(tl * KS + ks) * 64 + lane];
                a[ks] = u.h;
            }
            #pragma unroll
            for (int s = 0; s < 2; ++s) {
                f32x16 acc = {};
                #pragma unroll
                for (int ks = 0; ks < KS; ++ks)
                    acc = __builtin_amdgcn_mfma_f32_32x32x16_f16(a[ks], bfr[s][ks], acc, 0, 0, 0);

                // fused single-pass: top-3 values of the 16 regs + argmax reg.
                // b1 keeps the FIRST (lowest-r) maximum on ties.
                float b1 = NEGINF, b2 = NEGINF, b3 = NEGINF; int r1 = 0;
                #pragma unroll
                for (int r = 0; r < 16; ++r) {
                    float v = acc[r];
                    bool g1 = v > b1;
                    float l1 = g1 ? b1 : v;
                    bool g2 = l1 > b2;
                    float l2 = g2 ? b2 : l1;
                    b3 = fmaxf(b3, l2);
                    b2 = g2 ? l1 : b2;
                    b1 = g1 ? v : b1;
                    r1 = g1 ? r : r1;
                }
                if (b1 > lv[s][LCAP - 1]) {
                    ins4(lv[s], li[s], b1, m0 + ((r1 & 3) + 8 * (r1 >> 2) + 4 * hi));
                    if (b2 > lv[s][LCAP - 1]) {
                        int r2 = 15;
                        #pragma unroll
                        for (int r = 15; r >= 0; --r) {
                            bool e = (acc[r] == b2) && (r != r1);
                            r2 = e ? r : r2;   // reverse scan -> smallest matching r
                        }
                        ins4(lv[s], li[s], b2, m0 + ((r2 & 3) + 8 * (r2 >> 2) + 4 * hi));
                        if (b3 > lv[s][LCAP - 1]) {
                            int r3 = 15;
                            #pragma unroll
                            for (int r = 15; r >= 0; --r) {
                                bool e = (acc[r] == b3) && (r != r1) && (r != r2);
                                r3 = e ? r : r3;
                            }
                            ins4(lv[s], li[s], b3, m0 + ((r3 & 3) + 8 * (r3 >> 2) + 4 * hi));
                        }
                    }
                }
            }
        }
        __syncthreads();
    }

    // write candidate indices: cands[b][n][split][hi][4]
    #pragma unroll
    for (int s = 0; s < 2; ++s) {
        int nt = nb * 8 + w * 2 + s;
        int n = nt * 32 + lo;
        size_t base = (((size_t)b * N_ + n) * SPLIT + split) * (2 * LCAP) + hi * LCAP;
        #pragma unroll
        for (int k = 0; k < LCAP; ++k) cands[base + k] = (u16)li[s][k];
    }
}

// ---------------------------------------------------------------------------
// Kernel 3: exact rescore. One wave per src row; 1 candidate per lane.
// Dot = sequential fmaf over c (bit-identical to round-1 arithmetic).
// Robust to junk candidates: any valid index is scored exactly and can only
// lose to the true top-3 (which are guaranteed present).
// ---------------------------------------------------------------------------
__global__ __launch_bounds__(256)
void rescore(const u16* __restrict__ cands, const float* __restrict__ fx,
             const float* __restrict__ fynT, const float* __restrict__ nyeps,
             const float* __restrict__ minf,
             const unsigned char* __restrict__ mask1b,
             const int* __restrict__ flags, float* __restrict__ out) {
    int gw = blockIdx.x * 4 + (threadIdx.x >> 6);    // row = b*N + n
    int lane = threadIdx.x & 63;
    if (gw >= B_ * N_) return;
    int b = gw / N_, n = gw - b * N_;

    int idx = cands[(size_t)gw * CPR + lane];
    bool valid = idx < N_;
    int m = valid ? idx : 0;

    const float* fxb = fx + (size_t)b * C_ * N_ + n;   // fx[b][c][n], stride N_
    const float* fr = fynT + ((size_t)b * N_ + m) * C_;
    float a = 0.f;
    #pragma unroll 4
    for (int c = 0; c < C_; c += 4) {
        a = fmaf(fxb[(size_t)(c + 0) * N_], fr[c + 0], a);
        a = fmaf(fxb[(size_t)(c + 1) * N_], fr[c + 1], a);
        a = fmaf(fxb[(size_t)(c + 2) * N_], fr[c + 2], a);
        a = fmaf(fxb[(size_t)(c + 3) * N_], fr[c + 3], a);
    }
    float rnk = valid ? (a + minf[(size_t)b * N_ + m]) : NEGINF;
    float wgt = a * nyeps[(size_t)b * N_ + m];
    int  midx = valid ? idx : 0x7fffffff;

    int wi[3]; float ww[3];
    #pragma unroll
    for (int r = 0; r < 3; ++r) {
        float cv = rnk; int ci = midx; float cw = wgt;
        #pragma unroll
        for (int off = 32; off >= 1; off >>= 1) {
            float ov = __shfl_xor(cv, off);
            int   oi = __shfl_xor(ci, off);
            float ow = __shfl_xor(cw, off);
            bool take = (ov > cv) || (ov == cv && oi < ci);
            cv = take ? ov : cv; ci = take ? oi : ci; cw = take ? ow : cw;
        }
        wi[r] = ci; ww[r] = cw;
        if (midx == ci) rnk = NEGINF;   // remove winner (and any duplicates)
    }

    if (lane == 0) {
        float w0 = ww[0], w1 = ww[1], w2 = ww[2];
        float h0 = (float)(wi[0] / W_), h1 = (float)(wi[1] / W_), h2 = (float)(wi[2] / W_);
        float q0 = (float)(wi[0] % W_), q1 = (float)(wi[1] % W_), q2 = (float)(wi[2] % W_);
        float den = w0 + w1 + w2;
        float ph = (h0 * w0 + h1 * w1 + h2 * w2) / den;
        float pw = (q0 * w0 + q1 * w1 + q2 * w2) / den;
        bool m1 = flags[0] ? (mask1b[gw] != 0) : (((const int*)mask1b)[gw] != 0);
        out[2 * gw]     = m1 ? ph : -1.0f;
        out[2 * gw + 1] = m1 ? pw : -1.0f;
    }
}

// ---------------------------------------------------------------------------
// Kernel 4: slic gather.
// ---------------------------------------------------------------------------
__global__ void slic_gather(const float* __restrict__ spg,
                            const float* __restrict__ pred,
                            float* __restrict__ outg) {
    int t = blockIdx.x * blockDim.x + threadIdx.x;
    if (t >= B_ * S_ * G_) return;
    int b = t / (S_ * G_);
    float vh = spg[2 * t], vw = spg[2 * t + 1];
    int ph = (int)rintf(vh * (float)H_);
    int pw = (int)rintf(vw * (float)H_);
    ph = ph < 0 ? 0 : (ph > H_ - 1 ? H_ - 1 : ph);
    pw = pw < 0 ? 0 : (pw > H_ - 1 ? H_ - 1 : pw);
    int lin = ph * W_ + pw;
    outg[2 * t]     = pred[((size_t)b * N_ + lin) * 2]     / (float)H_;
    outg[2 * t + 1] = pred[((size_t)b * N_ + lin) * 2 + 1] / (float)H_;
}

extern "C" void kernel_launch(void* const* d_in, const int* in_sizes, int n_in,
                              void* d_out, int out_size, void* d_ws, size_t ws_size,
                              hipStream_t stream) {
    const float* img1 = (const float*)d_in[0];
    const float* img2 = (const float*)d_in[1];
    const void*  mask1 = d_in[2];
    const void*  mask2 = d_in[3];
    const float* spg = (const float*)d_in[4];
    float* out = (float*)d_out;

    char* ws = (char*)d_ws;
    size_t off = 0;
    int*   flags = (int*)(ws + off);            off += 256;
    float* fynT  = (float*)(ws + off);          off += (size_t)B_ * N_ * C_ * 4;       // 6.42 MB
    f16*   fxq   = (f16*)(ws + off);            off += (size_t)B_ * NT * KS * 64 * 16; // 4.01 MB
    f16*   fynq  = (f16*)(ws + off);            off += (size_t)B_ * MT * KS * 64 * 16; // 4.01 MB
    float* nyeps = (float*)(ws + off);          off += (size_t)B_ * N_ * 4;
    float* minf  = (float*)(ws + off);          off += (size_t)B_ * N_ * 4;
    u16*   cands = (u16*)(ws + off);            off += (size_t)B_ * N_ * CPR * 2;      // 3.21 MB

    detect_fmt<<<1, 256, 0, stream>>>((const unsigned char*)mask1, B_ * N_,
                                      (const unsigned char*)mask2, B_ * N_, flags);
    prepY<<<(B_ * N_) / 256, 256, 0, stream>>>(
        img2, (const unsigned char*)mask2, flags, fynT, fynq, nyeps, minf);
    prepX<<<(B_ * N_) / 256, 256, 0, stream>>>(img1, fxq);

    dim3 g1(49, SPLIT, B_);
    stage1<<<g1, 256, 0, stream>>>(fxq, fynq, cands);

    rescore<<<(B_ * N_) / 4, 256, 0, stream>>>(
        cands, img1, fynT, nyeps, minf, (const unsigned char*)mask1, flags, out);

    slic_gather<<<(B_ * S_ * G_ + 255) / 256, 256, 0, stream>>>(
        spg, out, out + (size_t)B_ * N_ * 2);
}

// Round 5
// 200.442 us; speedup vs baseline: 3.9975x; 1.8932x over previous
//
#include <hip/hip_runtime.h>
#include <math.h>

typedef _Float16 f16;
typedef f16 f16x8 __attribute__((ext_vector_type(8)));
typedef float f32x16 __attribute__((ext_vector_type(16)));
typedef unsigned short u16;
typedef unsigned int u32;

#define B_ 2
#define C_ 64
#define KS 5             // K-steps of 16: 64 feats + mask(k=64) + bias(k=65) + pad
#define H_ 112
#define W_ 112
#define N_ 12544
#define S_ 50
#define G_ 120
#define MT 392           // m-tiles of 32
#define NT 392           // n-subtiles of 32
#define SPLIT 8
#define TPS 49           // m-tiles per split
#define GROUP 2          // m-tiles staged per LDS group
#define NG 25            // ceil(49/2); last group has 1 tile
#define LCAP 4           // per-lane top-4 (exact rank <=3 + 1 noise-margin slot)
#define CPR (SPLIT*2*LCAP) // 64 candidates per row -> 1 per lane in rescore

#define NEGINF (-__builtin_inff())

union U16B { uint4 u; f16x8 h; f16 e[8]; };

__device__ __forceinline__ u32 umin_(u32 a, u32 b) { return a < b ? a : b; }
__device__ __forceinline__ u32 umax_(u32 a, u32 b) { return a > b ? a : b; }

__device__ __forceinline__ void glds16(const uint4* g, uint4* l) {
    __builtin_amdgcn_global_load_lds(
        (const __attribute__((address_space(1))) unsigned int*)g,
        (__attribute__((address_space(3))) unsigned int*)l, 16, 0, 0);
}

// 4-deep sorted insert (desc, u32 packed values + tile index). Caller
// guarantees v > lv[3]. Strict '>' keeps earlier-inserted ahead on ties.
__device__ __forceinline__ void ins4u(u32* lv, int* li, u32 v, int t) {
    bool g2 = v > lv[2], g1 = v > lv[1], g0 = v > lv[0];
    lv[3] = g2 ? lv[2] : v;                 li[3] = g2 ? li[2] : t;
    lv[2] = g2 ? (g1 ? lv[1] : v) : lv[2];  li[2] = g2 ? (g1 ? li[1] : t) : li[2];
    lv[1] = g1 ? (g0 ? lv[0] : v) : lv[1];  li[1] = g1 ? (g0 ? li[0] : t) : li[1];
    lv[0] = g0 ? v : lv[0];                 li[0] = g0 ? t : li[0];
}

// ---------------------------------------------------------------------------
// Kernel 0: bool-mask format detect, vectorized. For int32 0/1 data every
// word & 0xFFFFFF00 == 0; for byte bools ~half the bytes are 1. Reading the
// first 6272 words (= byte-format size) is sufficient and safe for both.
// ---------------------------------------------------------------------------
__global__ void detect_fmt(const u32* __restrict__ m1, const u32* __restrict__ m2,
                           int nw, int* __restrict__ flags) {
    __shared__ u32 s[2];
    if (threadIdx.x == 0) { s[0] = 0; s[1] = 0; }
    __syncthreads();
    u32 a = 0, bb = 0;
    for (int i = threadIdx.x; i < nw; i += blockDim.x) {
        a  |= m1[i] & 0xFFFFFF00u;
        bb |= m2[i] & 0xFFFFFF00u;
    }
    if (a)  atomicOr(&s[0], 1u);
    if (bb) atomicOr(&s[1], 1u);
    __syncthreads();
    if (threadIdx.x == 0) { flags[0] = s[0] ? 1 : 0; flags[1] = s[1] ? 1 : 0; }
}

// ---------------------------------------------------------------------------
// Kernel 1a: dst features — fp32 fynT rows (bitwise same math as round 1),
// fp16 frag-ordered fynq with mask channel (k=64: 0 valid / -96 masked) and
// bias channel (k=65: +128, makes every stage1 score positive), nyeps, minf.
// ---------------------------------------------------------------------------
__global__ void prepY(const float* __restrict__ fy,
                      const unsigned char* __restrict__ mask2b,
                      const int* __restrict__ flags,
                      float* __restrict__ fynT, f16* __restrict__ fynq,
                      float* __restrict__ nyeps, float* __restrict__ minf) {
    int t = blockIdx.x * blockDim.x + threadIdx.x;   // t = b*N + m
    if (t >= B_ * N_) return;
    int b = t / N_, m = t - b * N_;
    const float* src = fy + (size_t)b * C_ * N_ + m;
    float v[64];
    float ss = 0.f;
    #pragma unroll
    for (int c = 0; c < C_; ++c) { v[c] = src[(size_t)c * N_]; ss = fmaf(v[c], v[c], ss); }
    float ny = sqrtf(ss) + 1e-12f;
    nyeps[t] = ny;
    bool valid = flags[1] ? (mask2b[t] != 0) : (((const int*)mask2b)[t] != 0);
    minf[t] = valid ? 0.0f : NEGINF;
    float mval = valid ? 0.0f : -96.0f;

    float* dT = fynT + (size_t)t * C_;
    #pragma unroll
    for (int c = 0; c < C_; ++c) dT[c] = v[c] / ny;   // same arithmetic as round 1

    int tile = m >> 5, r = m & 31;
    uint4* q4 = (uint4*)fynq;
    size_t cb = (size_t)(b * MT + tile) * KS * 64;
    #pragma unroll
    for (int ks = 0; ks < KS; ++ks) {
        #pragma unroll
        for (int hi = 0; hi < 2; ++hi) {
            U16B tmp;
            #pragma unroll
            for (int i = 0; i < 8; ++i) {
                int k = 16 * ks + 8 * hi + i;
                float val = (k < 64) ? (v[k] / ny)
                          : ((k == 64) ? mval : ((k == 65) ? 128.0f : 0.0f));
                tmp.e[i] = (f16)val;
            }
            q4[cb + (size_t)ks * 64 + hi * 32 + r] = tmp.u;
        }
    }
}

// ---------------------------------------------------------------------------
// Kernel 1b: src features — fp16 frag-ordered fxq (k=64 and k=65 = 1.0).
// ---------------------------------------------------------------------------
__global__ void prepX(const float* __restrict__ fx, f16* __restrict__ fxq) {
    int t = blockIdx.x * blockDim.x + threadIdx.x;   // t = b*N + n
    if (t >= B_ * N_) return;
    int b = t / N_, n = t - b * N_;
    const float* src = fx + (size_t)b * C_ * N_ + n;
    float v[64];
    #pragma unroll
    for (int c = 0; c < C_; ++c) v[c] = src[(size_t)c * N_];

    int tile = n >> 5, r = n & 31;
    uint4* q4 = (uint4*)fxq;
    size_t cb = (size_t)(b * NT + tile) * KS * 64;
    #pragma unroll
    for (int ks = 0; ks < KS; ++ks) {
        #pragma unroll
        for (int hi = 0; hi < 2; ++hi) {
            U16B tmp;
            #pragma unroll
            for (int i = 0; i < 8; ++i) {
                int k = 16 * ks + 8 * hi + i;
                float val = (k < 64) ? v[k] : ((k <= 65) ? 1.0f : 0.0f);
                tmp.e[i] = (f16)val;
            }
            q4[cb + (size_t)ks * 64 + hi * 32 + r] = tmp.u;
        }
    }
}

// ---------------------------------------------------------------------------
// Kernel 2: MFMA candidate pass. 1 n-subtile per wave (grid 98x8x2 = 1568
// blocks for occupancy), GROUP=2 double-buffered LDS (20 KiB). Scores are
// biased positive (+128 channel) so f32 bits compare as u32; each value is
// packed (bits & ~0xF) | reg -> top-3-of-16 is a pure u32 min/max chain and
// inserts need no index-recovery scans. Cell-top-3 + per-lane top-4 keeps
// the round-4 coverage guarantee (exact rank <=3 + 1 noise-margin slot).
// ---------------------------------------------------------------------------
__global__ __launch_bounds__(256, 5)
void stage1(const f16* __restrict__ fxq, const f16* __restrict__ fynq,
            u16* __restrict__ cands) {
    __shared__ uint4 lds[2][GROUP * KS * 64];   // 2 x 10 KiB

    const int tid = threadIdx.x;
    const int lane = tid & 63, w = tid >> 6;
    const int lo = lane & 31, hi = lane >> 5;
    const int nb = blockIdx.x;          // 0..97
    const int split = blockIdx.y;
    const int b = blockIdx.z;
    const int tbase = split * TPS;

    const uint4* fxq4 = (const uint4*)fxq;
    const uint4* fyb  = (const uint4*)fynq + (size_t)(b * MT + tbase) * KS * 64;

    // resident B-fragments: fx for this wave's single n-subtile
    const int nt = nb * 4 + w;
    f16x8 bfr[KS];
    #pragma unroll
    for (int ks = 0; ks < KS; ++ks) {
        U16B u; u.u = fxq4[(size_t)((b * NT + nt) * KS + ks) * 64 + lane];
        bfr[ks] = u.h;
    }

    u32 lv[LCAP] = {0, 0, 0, 0};
    int li[LCAP] = {0xFFFF, 0xFFFF, 0xFFFF, 0xFFFF};

    // prologue: stage group 0 (2 tiles = 10 uint4-rows, split across 4 waves)
    for (int c = w; c < GROUP * KS; c += 4) {
        int tl = (c >= KS) ? 1 : 0;
        int ks = c - tl * KS;
        glds16(fyb + ((size_t)tl * KS + ks) * 64 + lane, &lds[0][c * 64]);
    }
    __syncthreads();

    for (int g = 0; g < NG; ++g) {
        const int cur = g & 1;
        if (g + 1 < NG) {
            int cntn = (g + 1 == NG - 1) ? (TPS - (NG - 1) * GROUP) : GROUP;
            int t0n = (g + 1) * GROUP;
            for (int c = w; c < cntn * KS; c += 4) {
                int tl = (c >= KS) ? 1 : 0;
                int ks = c - tl * KS;
                glds16(fyb + ((size_t)(t0n + tl) * KS + ks) * 64 + lane,
                       &lds[1 - cur][c * 64]);
            }
        }
        int cnt = (g == NG - 1) ? (TPS - (NG - 1) * GROUP) : GROUP;
        for (int tl = 0; tl < cnt; ++tl) {
            f16x8 a[KS];
            #pragma unroll
            for (int ks = 0; ks < KS; ++ks) {
                U16B u; u.u = lds[cur][(tl * KS + ks) * 64 + lane];
                a[ks] = u.h;
            }
            f32x16 acc = {};
            #pragma unroll
            for (int ks = 0; ks < KS; ++ks)
                acc = __builtin_amdgcn_mfma_f32_32x32x16_f16(a[ks], bfr[ks], acc, 0, 0, 0);

            // packed top-3-of-16: all values positive (bias ch) -> u32 order
            u32 b1 = 0, b2 = 0, b3 = 0;
            #pragma unroll
            for (int r = 0; r < 16; ++r) {
                u32 p = (__float_as_uint(acc[r]) & 0xFFFFFFF0u) | (u32)r;
                b3 = umax_(b3, umin_(p, b2));
                b2 = umax_(b2, umin_(p, b1));
                b1 = umax_(b1, p);
            }
            if (b1 > lv[LCAP - 1]) {
                int t = g * GROUP + tl;   // tile index within split (0..48)
                ins4u(lv, li, b1, t);
                if (b2 > lv[LCAP - 1]) {
                    ins4u(lv, li, b2, t);
                    if (b3 > lv[LCAP - 1]) ins4u(lv, li, b3, t);
                }
            }
        }
        __syncthreads();
    }

    // write candidate indices: cands[b][n][split][hi][4]
    int n = nt * 32 + lo;
    size_t base = (((size_t)b * N_ + n) * SPLIT + split) * (2 * LCAP) + hi * LCAP;
    #pragma unroll
    for (int k = 0; k < LCAP; ++k) {
        int r = (int)(lv[k] & 15u);
        int row = (r & 3) + ((r & 12) << 1) + 4 * hi;   // = (r&3) + 8*(r>>2) + 4*hi
        int m = (tbase + li[k]) * 32 + row;
        cands[base + k] = (li[k] == 0xFFFF) ? (u16)0xFFFF : (u16)m;
    }
}

// ---------------------------------------------------------------------------
// Kernel 3: exact rescore. One wave per src row; 1 candidate per lane.
// Dot = sequential fmaf over c (bit-identical to round-1 arithmetic; fr via
// float4 loads, same operand order). Junk candidates score exactly and can
// only lose to the guaranteed-present true top-3.
// ---------------------------------------------------------------------------
__global__ __launch_bounds__(256)
void rescore(const u16* __restrict__ cands, const float* __restrict__ fx,
             const float* __restrict__ fynT, const float* __restrict__ nyeps,
             const float* __restrict__ minf,
             const unsigned char* __restrict__ mask1b,
             const int* __restrict__ flags, float* __restrict__ out) {
    int gw = blockIdx.x * 4 + (threadIdx.x >> 6);    // row = b*N + n
    int lane = threadIdx.x & 63;
    if (gw >= B_ * N_) return;
    int b = gw / N_, n = gw - b * N_;

    int idx = cands[(size_t)gw * CPR + lane];
    bool valid = idx < N_;
    int m = valid ? idx : 0;

    const float* fxb = fx + (size_t)b * C_ * N_ + n;   // fx[b][c][n], stride N_
    const float4* fr4 = (const float4*)(fynT + ((size_t)b * N_ + m) * C_);
    float a = 0.f;
    #pragma unroll
    for (int c4 = 0; c4 < 16; ++c4) {
        float4 f = fr4[c4];
        int c = c4 * 4;
        a = fmaf(fxb[(size_t)(c + 0) * N_], f.x, a);
        a = fmaf(fxb[(size_t)(c + 1) * N_], f.y, a);
        a = fmaf(fxb[(size_t)(c + 2) * N_], f.z, a);
        a = fmaf(fxb[(size_t)(c + 3) * N_], f.w, a);
    }
    float rnk = valid ? (a + minf[(size_t)b * N_ + m]) : NEGINF;
    float wgt = a * nyeps[(size_t)b * N_ + m];
    int  midx = valid ? idx : 0x7fffffff;

    int wi[3]; float ww[3];
    #pragma unroll
    for (int r = 0; r < 3; ++r) {
        float cv = rnk; int ci = midx; float cw = wgt;
        #pragma unroll
        for (int off = 32; off >= 1; off >>= 1) {
            float ov = __shfl_xor(cv, off);
            int   oi = __shfl_xor(ci, off);
            float ow = __shfl_xor(cw, off);
            bool take = (ov > cv) || (ov == cv && oi < ci);
            cv = take ? ov : cv; ci = take ? oi : ci; cw = take ? ow : cw;
        }
        wi[r] = ci; ww[r] = cw;
        if (midx == ci) rnk = NEGINF;   // remove winner (and duplicates)
    }

    if (lane == 0) {
        float w0 = ww[0], w1 = ww[1], w2 = ww[2];
        float h0 = (float)(wi[0] / W_), h1 = (float)(wi[1] / W_), h2 = (float)(wi[2] / W_);
        float q0 = (float)(wi[0] % W_), q1 = (float)(wi[1] % W_), q2 = (float)(wi[2] % W_);
        float den = w0 + w1 + w2;
        float ph = (h0 * w0 + h1 * w1 + h2 * w2) / den;
        float pw = (q0 * w0 + q1 * w1 + q2 * w2) / den;
        bool m1 = flags[0] ? (mask1b[gw] != 0) : (((const int*)mask1b)[gw] != 0);
        out[2 * gw]     = m1 ? ph : -1.0f;
        out[2 * gw + 1] = m1 ? pw : -1.0f;
    }
}

// ---------------------------------------------------------------------------
// Kernel 4: slic gather.
// ---------------------------------------------------------------------------
__global__ void slic_gather(const float* __restrict__ spg,
                            const float* __restrict__ pred,
                            float* __restrict__ outg) {
    int t = blockIdx.x * blockDim.x + threadIdx.x;
    if (t >= B_ * S_ * G_) return;
    int b = t / (S_ * G_);
    float vh = spg[2 * t], vw = spg[2 * t + 1];
    int ph = (int)rintf(vh * (float)H_);
    int pw = (int)rintf(vw * (float)H_);
    ph = ph < 0 ? 0 : (ph > H_ - 1 ? H_ - 1 : ph);
    pw = pw < 0 ? 0 : (pw > H_ - 1 ? H_ - 1 : pw);
    int lin = ph * W_ + pw;
    outg[2 * t]     = pred[((size_t)b * N_ + lin) * 2]     / (float)H_;
    outg[2 * t + 1] = pred[((size_t)b * N_ + lin) * 2 + 1] / (float)H_;
}

extern "C" void kernel_launch(void* const* d_in, const int* in_sizes, int n_in,
                              void* d_out, int out_size, void* d_ws, size_t ws_size,
                              hipStream_t stream) {
    const float* img1 = (const float*)d_in[0];
    const float* img2 = (const float*)d_in[1];
    const void*  mask1 = d_in[2];
    const void*  mask2 = d_in[3];
    const float* spg = (const float*)d_in[4];
    float* out = (float*)d_out;

    char* ws = (char*)d_ws;
    size_t off = 0;
    int*   flags = (int*)(ws + off);            off += 256;
    float* fynT  = (float*)(ws + off);          off += (size_t)B_ * N_ * C_ * 4;       // 6.42 MB
    f16*   fxq   = (f16*)(ws + off);            off += (size_t)B_ * NT * KS * 64 * 16; // 4.01 MB
    f16*   fynq  = (f16*)(ws + off);            off += (size_t)B_ * MT * KS * 64 * 16; // 4.01 MB
    float* nyeps = (float*)(ws + off);          off += (size_t)B_ * N_ * 4;
    float* minf  = (float*)(ws + off);          off += (size_t)B_ * N_ * 4;
    u16*   cands = (u16*)(ws + off);            off += (size_t)B_ * N_ * CPR * 2;      // 3.21 MB

    detect_fmt<<<1, 1024, 0, stream>>>((const u32*)mask1, (const u32*)mask2,
                                       (B_ * N_) / 4, flags);
    prepX<<<(B_ * N_) / 256, 256, 0, stream>>>(img1, fxq);
    prepY<<<(B_ * N_) / 256, 256, 0, stream>>>(
        img2, (const unsigned char*)mask2, flags, fynT, fynq, nyeps, minf);

    dim3 g1(98, SPLIT, B_);
    stage1<<<g1, 256, 0, stream>>>(fxq, fynq, cands);

    rescore<<<(B_ * N_) / 4, 256, 0, stream>>>(
        cands, img1, fynT, nyeps, minf, (const unsigned char*)mask1, flags, out);

    slic_gather<<<(B_ * S_ * G_ + 255) / 256, 256, 0, stream>>>(
        spg, out, out + (size_t)B_ * N_ * 2);
}

// Round 6
// 156.222 us; speedup vs baseline: 5.1290x; 1.2831x over previous
//
#include <hip/hip_runtime.h>
#include <math.h>

typedef _Float16 f16;
typedef f16 f16x8 __attribute__((ext_vector_type(8)));
typedef float f32x16 __attribute__((ext_vector_type(16)));
typedef unsigned short u16;
typedef unsigned int u32;

#define B_ 2
#define C_ 64
#define KS 5             // K-steps of 16: 64 feats + mask(k=64) + bias(k=65) + pad
#define H_ 112
#define W_ 112
#define N_ 12544
#define S_ 50
#define G_ 120
#define MT 392           // m-tiles of 32
#define NT 392           // n-subtiles of 32
#define SPLIT 8
#define TPS 49           // m-tiles per split
#define LCAP 4           // per-lane top-4 (exact rank <=3 + 1 noise-margin slot)
#define CPR (SPLIT*2*LCAP) // 64 candidates per row -> 1 per lane in rescore

#define NEGINF (-__builtin_inff())

union U16B { uint4 u; f16x8 h; f16 e[8]; };

// 4-deep sorted insert (desc, float packed values + tile index). Caller
// guarantees v > lv[3]. Strict '>' keeps earlier-inserted ahead on ties.
__device__ __forceinline__ void ins4f(float* lv, int* li, float v, int t) {
    bool g2 = v > lv[2], g1 = v > lv[1], g0 = v > lv[0];
    lv[3] = g2 ? lv[2] : v;                 li[3] = g2 ? li[2] : t;
    lv[2] = g2 ? (g1 ? lv[1] : v) : lv[2];  li[2] = g2 ? (g1 ? li[1] : t) : li[2];
    lv[1] = g1 ? (g0 ? lv[0] : v) : lv[1];  li[1] = g1 ? (g0 ? li[0] : t) : li[1];
    lv[0] = g0 ? v : lv[0];                 li[0] = g0 ? t : li[0];
}

// ---------------------------------------------------------------------------
// Kernel 0: bool-mask format detect (byte vs int32), vectorized word test.
// ---------------------------------------------------------------------------
__global__ void detect_fmt(const u32* __restrict__ m1, const u32* __restrict__ m2,
                           int nw, int* __restrict__ flags) {
    __shared__ u32 s[2];
    if (threadIdx.x == 0) { s[0] = 0; s[1] = 0; }
    __syncthreads();
    u32 a = 0, bb = 0;
    for (int i = threadIdx.x; i < nw; i += blockDim.x) {
        a  |= m1[i] & 0xFFFFFF00u;
        bb |= m2[i] & 0xFFFFFF00u;
    }
    if (a)  atomicOr(&s[0], 1u);
    if (bb) atomicOr(&s[1], 1u);
    __syncthreads();
    if (threadIdx.x == 0) { flags[0] = s[0] ? 1 : 0; flags[1] = s[1] ? 1 : 0; }
}

// ---------------------------------------------------------------------------
// Kernel 1a: dst features — fp32 fynT rows (bitwise same math as round 1),
// fp16 frag-ordered fynq with mask channel (k=64: 0 valid / -96 masked) and
// bias channel (k=65: +128 -> every stage1 score positive), nyeps, minf.
// ---------------------------------------------------------------------------
__global__ void prepY(const float* __restrict__ fy,
                      const unsigned char* __restrict__ mask2b,
                      const int* __restrict__ flags,
                      float* __restrict__ fynT, f16* __restrict__ fynq,
                      float* __restrict__ nyeps, float* __restrict__ minf) {
    int t = blockIdx.x * blockDim.x + threadIdx.x;   // t = b*N + m
    if (t >= B_ * N_) return;
    int b = t / N_, m = t - b * N_;
    const float* src = fy + (size_t)b * C_ * N_ + m;
    float v[64];
    float ss = 0.f;
    #pragma unroll
    for (int c = 0; c < C_; ++c) { v[c] = src[(size_t)c * N_]; ss = fmaf(v[c], v[c], ss); }
    float ny = sqrtf(ss) + 1e-12f;
    nyeps[t] = ny;
    bool valid = flags[1] ? (mask2b[t] != 0) : (((const int*)mask2b)[t] != 0);
    minf[t] = valid ? 0.0f : NEGINF;
    float mval = valid ? 0.0f : -96.0f;

    float* dT = fynT + (size_t)t * C_;
    #pragma unroll
    for (int c = 0; c < C_; ++c) dT[c] = v[c] / ny;   // same arithmetic as round 1

    int tile = m >> 5, r = m & 31;
    uint4* q4 = (uint4*)fynq;
    size_t cb = (size_t)(b * MT + tile) * KS * 64;
    #pragma unroll
    for (int ks = 0; ks < KS; ++ks) {
        #pragma unroll
        for (int hi = 0; hi < 2; ++hi) {
            U16B tmp;
            #pragma unroll
            for (int i = 0; i < 8; ++i) {
                int k = 16 * ks + 8 * hi + i;
                float val = (k < 64) ? (v[k] / ny)
                          : ((k == 64) ? mval : ((k == 65) ? 128.0f : 0.0f));
                tmp.e[i] = (f16)val;
            }
            q4[cb + (size_t)ks * 64 + hi * 32 + r] = tmp.u;
        }
    }
}

// ---------------------------------------------------------------------------
// Kernel 1b: src features — fp16 frag-ordered fxq (k=64 and k=65 = 1.0).
// ---------------------------------------------------------------------------
__global__ void prepX(const float* __restrict__ fx, f16* __restrict__ fxq) {
    int t = blockIdx.x * blockDim.x + threadIdx.x;   // t = b*N + n
    if (t >= B_ * N_) return;
    int b = t / N_, n = t - b * N_;
    const float* src = fx + (size_t)b * C_ * N_ + n;
    float v[64];
    #pragma unroll
    for (int c = 0; c < C_; ++c) v[c] = src[(size_t)c * N_];

    int tile = n >> 5, r = n & 31;
    uint4* q4 = (uint4*)fxq;
    size_t cb = (size_t)(b * NT + tile) * KS * 64;
    #pragma unroll
    for (int ks = 0; ks < KS; ++ks) {
        #pragma unroll
        for (int hi = 0; hi < 2; ++hi) {
            U16B tmp;
            #pragma unroll
            for (int i = 0; i < 8; ++i) {
                int k = 16 * ks + 8 * hi + i;
                float val = (k < 64) ? v[k] : ((k <= 65) ? 1.0f : 0.0f);
                tmp.e[i] = (f16)val;
            }
            q4[cb + (size_t)ks * 64 + hi * 32 + r] = tmp.u;
        }
    }
}

// ---------------------------------------------------------------------------
// Kernel 2: MFMA candidate pass, no LDS / no barriers. Per-wave register
// double-buffer (aA/aB, unroll-by-2 for static indexing) streams the split's
// 49 m-tiles straight from L2 (250 KB panel, shared by 98 blocks -> cached).
// Extraction: pack reg-index into low 4 bits of the positive (bias +128)
// f32 score; cell-top-3 via fmed3 chain (3 ops/value); rare guarded inserts
// into per-lane sorted top-4. Outputs packed noisy values AND m-indices.
// ---------------------------------------------------------------------------
#define LDA(dst, t) { _Pragma("unroll") \
    for (int ks = 0; ks < KS; ++ks) { \
        U16B u_; u_.u = fyb[((size_t)(t) * KS + ks) * 64]; dst[ks] = u_.h; } }

#define CELL(a, t) { \
    f32x16 acc = {}; \
    _Pragma("unroll") \
    for (int ks = 0; ks < KS; ++ks) \
        acc = __builtin_amdgcn_mfma_f32_32x32x16_f16(a[ks], bfr[ks], acc, 0, 0, 0); \
    float b1 = 0.f, b2 = 0.f, b3 = 0.f; \
    _Pragma("unroll") \
    for (int r = 0; r < 16; ++r) { \
        float p = __uint_as_float((__float_as_uint(acc[r]) & 0xFFFFFFF0u) | (u32)r); \
        float n3 = __builtin_amdgcn_fmed3f(p, b2, b3); \
        float n2 = __builtin_amdgcn_fmed3f(p, b1, b2); \
        b1 = fmaxf(p, b1); b2 = n2; b3 = n3; } \
    if (b1 > lv[3]) { ins4f(lv, li, b1, (t)); \
        if (b2 > lv[3]) { ins4f(lv, li, b2, (t)); \
            if (b3 > lv[3]) ins4f(lv, li, b3, (t)); } } }

__global__ __launch_bounds__(256)
void stage1(const f16* __restrict__ fxq, const f16* __restrict__ fynq,
            u32* __restrict__ cvals, u16* __restrict__ cidx) {
    const int tid = threadIdx.x;
    const int lane = tid & 63, w = tid >> 6;
    const int lo = lane & 31, hi = lane >> 5;
    const int nb = blockIdx.x;          // 0..97
    const int split = blockIdx.y;
    const int b = blockIdx.z;
    const int tbase = split * TPS;

    const uint4* fxq4 = (const uint4*)fxq;
    const uint4* fyb  = (const uint4*)fynq + ((size_t)(b * MT + tbase) * KS) * 64 + lane;

    // resident B-fragments: fx for this wave's n-subtile
    const int nt = nb * 4 + w;
    f16x8 bfr[KS];
    #pragma unroll
    for (int ks = 0; ks < KS; ++ks) {
        U16B u; u.u = fxq4[((size_t)((b * NT + nt) * KS + ks)) * 64 + lane];
        bfr[ks] = u.h;
    }

    float lv[LCAP] = {0.f, 0.f, 0.f, 0.f};
    int   li[LCAP] = {-1, -1, -1, -1};

    f16x8 aA[KS], aB[KS];
    LDA(aA, 0);
    for (int t = 0; t < TPS - 1; t += 2) {   // t = 0,2,...,46
        LDA(aB, t + 1);
        CELL(aA, t);
        LDA(aA, t + 2);                      // t+2 <= 48, always valid
        CELL(aB, t + 1);
    }
    CELL(aA, TPS - 1);                       // tile 48

    // write candidates: [b][n][split][hi][4] -> packed val + m index
    int n = nt * 32 + lo;
    size_t base = (((size_t)(b * N_ + n) * SPLIT + split) * 2 + hi) * LCAP;
    #pragma unroll
    for (int k = 0; k < LCAP; ++k) {
        u32 pb = __float_as_uint(lv[k]);
        int r = (int)(pb & 15u);
        int m = (tbase + li[k]) * 32 + ((r & 3) + ((r >> 2) << 3) + (hi << 2));
        cvals[base + k] = pb;
        cidx[base + k] = (li[k] < 0) ? (u16)0xFFFF : (u16)m;
    }
}

// ---------------------------------------------------------------------------
// Kernel 3: selective exact rescore. One wave per row, 1 candidate/lane.
// 3 wave-max rounds on noisy packed values -> t3; only lanes with
// vn >= t3 - 0.125 (noise bound 0.017, 7x margin; provably includes the
// true top-3) recompute the bit-identical round-1 fp32 dot. Exact selection
// (tie: lower index) + exact weights -> absmax 0 preserved.
// ---------------------------------------------------------------------------
__global__ __launch_bounds__(256)
void rescore(const u32* __restrict__ cvals, const u16* __restrict__ cidx,
             const float* __restrict__ fx, const float* __restrict__ fynT,
             const float* __restrict__ nyeps, const float* __restrict__ minf,
             const unsigned char* __restrict__ mask1b,
             const int* __restrict__ flags, float* __restrict__ out) {
    int gw = blockIdx.x * 4 + (threadIdx.x >> 6);    // row = b*N + n  (grid exact)
    int lane = threadIdx.x & 63;
    int b = gw / N_, n = gw - b * N_;

    float vn = __uint_as_float(cvals[(size_t)gw * CPR + lane]);
    int idx = cidx[(size_t)gw * CPR + lane];
    bool valid = idx < N_;

    // 3rd-largest noisy value (ties knock out together -> redo set only grows)
    float cur = valid ? vn : NEGINF;
    float t3 = NEGINF;
    #pragma unroll
    for (int r = 0; r < 3; ++r) {
        float c = cur;
        #pragma unroll
        for (int off = 32; off >= 1; off >>= 1) c = fmaxf(c, __shfl_xor(c, off));
        t3 = c;
        cur = (cur == c) ? NEGINF : cur;
    }
    bool redo = valid && (vn >= t3 - 0.125f);

    float rnk = NEGINF, wgt = 0.f;
    if (redo) {
        const float* fxb = fx + (size_t)b * C_ * N_ + n;   // fx[b][c][n], stride N_
        const float4* fr4 = (const float4*)(fynT + ((size_t)b * N_ + idx) * C_);
        float a = 0.f;
        #pragma unroll
        for (int c4 = 0; c4 < 16; ++c4) {
            float4 f = fr4[c4];
            int c = c4 * 4;
            a = fmaf(fxb[(size_t)(c + 0) * N_], f.x, a);
            a = fmaf(fxb[(size_t)(c + 1) * N_], f.y, a);
            a = fmaf(fxb[(size_t)(c + 2) * N_], f.z, a);
            a = fmaf(fxb[(size_t)(c + 3) * N_], f.w, a);
        }
        rnk = a + minf[(size_t)b * N_ + idx];
        wgt = a * nyeps[(size_t)b * N_ + idx];
    }
    int midx = redo ? idx : 0x7fffffff;

    int wi[3]; float ww[3];
    #pragma unroll
    for (int r = 0; r < 3; ++r) {
        float cv = rnk; int ci = midx; float cw = wgt;
        #pragma unroll
        for (int off = 32; off >= 1; off >>= 1) {
            float ov = __shfl_xor(cv, off);
            int   oi = __shfl_xor(ci, off);
            float ow = __shfl_xor(cw, off);
            bool take = (ov > cv) || (ov == cv && oi < ci);
            cv = take ? ov : cv; ci = take ? oi : ci; cw = take ? ow : cw;
        }
        wi[r] = ci; ww[r] = cw;
        if (midx == ci) rnk = NEGINF;   // remove winner (and duplicates)
    }

    if (lane == 0) {
        float w0 = ww[0], w1 = ww[1], w2 = ww[2];
        float h0 = (float)(wi[0] / W_), h1 = (float)(wi[1] / W_), h2 = (float)(wi[2] / W_);
        float q0 = (float)(wi[0] % W_), q1 = (float)(wi[1] % W_), q2 = (float)(wi[2] % W_);
        float den = w0 + w1 + w2;
        float ph = (h0 * w0 + h1 * w1 + h2 * w2) / den;
        float pw = (q0 * w0 + q1 * w1 + q2 * w2) / den;
        bool m1 = flags[0] ? (mask1b[gw] != 0) : (((const int*)mask1b)[gw] != 0);
        out[2 * gw]     = m1 ? ph : -1.0f;
        out[2 * gw + 1] = m1 ? pw : -1.0f;
    }
}

// ---------------------------------------------------------------------------
// Kernel 4: slic gather.
// ---------------------------------------------------------------------------
__global__ void slic_gather(const float* __restrict__ spg,
                            const float* __restrict__ pred,
                            float* __restrict__ outg) {
    int t = blockIdx.x * blockDim.x + threadIdx.x;
    if (t >= B_ * S_ * G_) return;
    int b = t / (S_ * G_);
    float vh = spg[2 * t], vw = spg[2 * t + 1];
    int ph = (int)rintf(vh * (float)H_);
    int pw = (int)rintf(vw * (float)H_);
    ph = ph < 0 ? 0 : (ph > H_ - 1 ? H_ - 1 : ph);
    pw = pw < 0 ? 0 : (pw > H_ - 1 ? H_ - 1 : pw);
    int lin = ph * W_ + pw;
    outg[2 * t]     = pred[((size_t)b * N_ + lin) * 2]     / (float)H_;
    outg[2 * t + 1] = pred[((size_t)b * N_ + lin) * 2 + 1] / (float)H_;
}

extern "C" void kernel_launch(void* const* d_in, const int* in_sizes, int n_in,
                              void* d_out, int out_size, void* d_ws, size_t ws_size,
                              hipStream_t stream) {
    const float* img1 = (const float*)d_in[0];
    const float* img2 = (const float*)d_in[1];
    const void*  mask1 = d_in[2];
    const void*  mask2 = d_in[3];
    const float* spg = (const float*)d_in[4];
    float* out = (float*)d_out;

    char* ws = (char*)d_ws;
    size_t off = 0;
    int*   flags = (int*)(ws + off);            off += 256;
    float* fynT  = (float*)(ws + off);          off += (size_t)B_ * N_ * C_ * 4;       // 6.42 MB
    f16*   fxq   = (f16*)(ws + off);            off += (size_t)B_ * NT * KS * 64 * 16; // 4.01 MB
    f16*   fynq  = (f16*)(ws + off);            off += (size_t)B_ * MT * KS * 64 * 16; // 4.01 MB
    float* nyeps = (float*)(ws + off);          off += (size_t)B_ * N_ * 4;
    float* minf  = (float*)(ws + off);          off += (size_t)B_ * N_ * 4;
    u32*   cvals = (u32*)(ws + off);            off += (size_t)B_ * N_ * CPR * 4;      // 6.42 MB
    u16*   cidx  = (u16*)(ws + off);            off += (size_t)B_ * N_ * CPR * 2;      // 3.21 MB

    detect_fmt<<<1, 1024, 0, stream>>>((const u32*)mask1, (const u32*)mask2,
                                       (B_ * N_) / 4, flags);
    prepX<<<(B_ * N_) / 256, 256, 0, stream>>>(img1, fxq);
    prepY<<<(B_ * N_) / 256, 256, 0, stream>>>(
        img2, (const unsigned char*)mask2, flags, fynT, fynq, nyeps, minf);

    dim3 g1(98, SPLIT, B_);
    stage1<<<g1, 256, 0, stream>>>(fxq, fynq, cvals, cidx);

    rescore<<<(B_ * N_) / 4, 256, 0, stream>>>(
        cvals, cidx, img1, fynT, nyeps, minf,
        (const unsigned char*)mask1, flags, out);

    slic_gather<<<(B_ * S_ * G_ + 255) / 256, 256, 0, stream>>>(
        spg, out, out + (size_t)B_ * N_ * 2);
}

// Round 7
// 150.114 us; speedup vs baseline: 5.3377x; 1.0407x over previous
//
#include <hip/hip_runtime.h>
#include <math.h>

typedef _Float16 f16;
typedef f16 f16x8 __attribute__((ext_vector_type(8)));
typedef float f32x16 __attribute__((ext_vector_type(16)));
typedef unsigned short u16;
typedef unsigned int u32;

#define B_ 2
#define C_ 64
#define KS 5             // K-steps of 16: 64 feats + mask(k=64) + bias(k=65) + pad
#define H_ 112
#define W_ 112
#define N_ 12544
#define S_ 50
#define G_ 120
#define MT 392           // m-tiles of 32
#define NT 392           // n-subtiles of 32
#define SPLIT 8
#define TPS 49           // m-tiles per split
#define LCAP 4           // per-lane-half top-4 (exact, branch-free)
#define CPR (SPLIT*2*LCAP) // 64 candidates per row -> 1 per lane in rescore

#define NEGINF (-__builtin_inff())

union U16B { uint4 u; f16x8 h; f16 e[8]; };

// ---------------------------------------------------------------------------
// Kernel 0: bool-mask format detect (byte vs int32), vectorized word test.
// ---------------------------------------------------------------------------
__global__ void detect_fmt(const u32* __restrict__ m1, const u32* __restrict__ m2,
                           int nw, int* __restrict__ flags) {
    __shared__ u32 s[2];
    if (threadIdx.x == 0) { s[0] = 0; s[1] = 0; }
    __syncthreads();
    u32 a = 0, bb = 0;
    for (int i = threadIdx.x; i < nw; i += blockDim.x) {
        a  |= m1[i] & 0xFFFFFF00u;
        bb |= m2[i] & 0xFFFFFF00u;
    }
    if (a)  atomicOr(&s[0], 1u);
    if (bb) atomicOr(&s[1], 1u);
    __syncthreads();
    if (threadIdx.x == 0) { flags[0] = s[0] ? 1 : 0; flags[1] = s[1] ? 1 : 0; }
}

// ---------------------------------------------------------------------------
// Kernel 1 (fused): blockIdx.y==0 -> src features (fxq, frag order, k=64/65
// channels = 1.0).  blockIdx.y==1 -> dst features: fp32 fynT rows (bitwise
// same math as round 1), fp16 frag-ordered fynq with mask channel (k=64:
// 0 valid / -96 masked) and bias channel (k=65: +128 -> scores positive),
// nyeps, minf.
// ---------------------------------------------------------------------------
__global__ void prep(const float* __restrict__ fx, const float* __restrict__ fy,
                     const unsigned char* __restrict__ mask2b,
                     const int* __restrict__ flags,
                     f16* __restrict__ fxq, float* __restrict__ fynT,
                     f16* __restrict__ fynq, float* __restrict__ nyeps,
                     float* __restrict__ minf) {
    int t = blockIdx.x * blockDim.x + threadIdx.x;   // t = b*N + pixel
    if (t >= B_ * N_) return;
    int b = t / N_, m = t - b * N_;
    int tile = m >> 5, r = m & 31;

    if (blockIdx.y == 0) {
        const float* src = fx + (size_t)b * C_ * N_ + m;
        float v[64];
        #pragma unroll
        for (int c = 0; c < C_; ++c) v[c] = src[(size_t)c * N_];
        uint4* q4 = (uint4*)fxq;
        size_t cb = (size_t)(b * NT + tile) * KS * 64;
        #pragma unroll
        for (int ks = 0; ks < KS; ++ks) {
            #pragma unroll
            for (int hi = 0; hi < 2; ++hi) {
                U16B tmp;
                #pragma unroll
                for (int i = 0; i < 8; ++i) {
                    int k = 16 * ks + 8 * hi + i;
                    float val = (k < 64) ? v[k] : ((k <= 65) ? 1.0f : 0.0f);
                    tmp.e[i] = (f16)val;
                }
                q4[cb + (size_t)ks * 64 + hi * 32 + r] = tmp.u;
            }
        }
    } else {
        const float* src = fy + (size_t)b * C_ * N_ + m;
        float v[64];
        float ss = 0.f;
        #pragma unroll
        for (int c = 0; c < C_; ++c) { v[c] = src[(size_t)c * N_]; ss = fmaf(v[c], v[c], ss); }
        float ny = sqrtf(ss) + 1e-12f;
        nyeps[t] = ny;
        bool valid = flags[1] ? (mask2b[t] != 0) : (((const int*)mask2b)[t] != 0);
        minf[t] = valid ? 0.0f : NEGINF;
        float mval = valid ? 0.0f : -96.0f;

        float* dT = fynT + (size_t)t * C_;
        #pragma unroll
        for (int c = 0; c < C_; ++c) dT[c] = v[c] / ny;   // round-1 arithmetic

        uint4* q4 = (uint4*)fynq;
        size_t cb = (size_t)(b * MT + tile) * KS * 64;
        #pragma unroll
        for (int ks = 0; ks < KS; ++ks) {
            #pragma unroll
            for (int hi = 0; hi < 2; ++hi) {
                U16B tmp;
                #pragma unroll
                for (int i = 0; i < 8; ++i) {
                    int k = 16 * ks + 8 * hi + i;
                    float val = (k < 64) ? (v[k] / ny)
                              : ((k == 64) ? mval : ((k == 65) ? 128.0f : 0.0f));
                    tmp.e[i] = (f16)val;
                }
                q4[cb + (size_t)ks * 64 + hi * 32 + r] = tmp.u;
            }
        }
    }
}

// ---------------------------------------------------------------------------
// Kernel 2: MFMA candidate pass — branch-free. Register double-buffer
// streams the split's 49 m-tiles from L2. Every score is positive (bias
// +128 channel; scores in [123,133], masked ~[27,37]) so f32 order == u32
// order. Each value packs a 10-bit (tile*16+reg) index into the mantissa
// low bits (grain 0.0156 << rescore margin 0.125), then a med3 chain keeps
// the EXACT top-4 packed values of the lane-half's 784-value stream --
// no per-cell policy, no guarded inserts, no wave-divergent paths.
// Coverage: a true top-3 of the row ranks <=3 within its own lane-half
// stream, so it is always among that lane-half's top-4 (up to ~0.02 noise,
// absorbed by rescore's 0.125 recheck band).
// ---------------------------------------------------------------------------
#define LDA(dst, t) { _Pragma("unroll") \
    for (int ks = 0; ks < KS; ++ks) { \
        U16B u_; u_.u = fyb[((size_t)(t) * KS + ks) * 64]; dst[ks] = u_.h; } }

#define CELL(a, t) { \
    f32x16 acc = {}; \
    _Pragma("unroll") \
    for (int ks = 0; ks < KS; ++ks) \
        acc = __builtin_amdgcn_mfma_f32_32x32x16_f16(a[ks], bfr[ks], acc, 0, 0, 0); \
    _Pragma("unroll") \
    for (int r = 0; r < 16; ++r) { \
        u32 pb_ = (__float_as_uint(acc[r]) & 0xFFFFFC00u) | (u32)((t) * 16 + r); \
        float p_ = __uint_as_float(pb_); \
        b4 = __builtin_amdgcn_fmed3f(p_, b3, b4); \
        b3 = __builtin_amdgcn_fmed3f(p_, b2, b3); \
        b2 = __builtin_amdgcn_fmed3f(p_, b1, b2); \
        b1 = fmaxf(p_, b1); } }

__global__ __launch_bounds__(256, 4)
void stage1(const f16* __restrict__ fxq, const f16* __restrict__ fynq,
            u32* __restrict__ cvals, u16* __restrict__ cidx) {
    const int tid = threadIdx.x;
    const int lane = tid & 63, w = tid >> 6;
    const int lo = lane & 31, hi = lane >> 5;
    const int nb = blockIdx.x;          // 0..97
    const int split = blockIdx.y;
    const int b = blockIdx.z;
    const int tbase = split * TPS;

    const uint4* fxq4 = (const uint4*)fxq;
    const uint4* fyb  = (const uint4*)fynq + ((size_t)(b * MT + tbase) * KS) * 64 + lane;

    // resident B-fragments: fx for this wave's n-subtile
    const int nt = nb * 4 + w;
    f16x8 bfr[KS];
    #pragma unroll
    for (int ks = 0; ks < KS; ++ks) {
        U16B u; u.u = fxq4[((size_t)((b * NT + nt) * KS + ks)) * 64 + lane];
        bfr[ks] = u.h;
    }

    float b1 = 0.f, b2 = 0.f, b3 = 0.f, b4 = 0.f;

    f16x8 aA[KS], aB[KS];
    LDA(aA, 0);
    for (int t = 0; t < TPS - 1; t += 2) {   // t = 0,2,...,46
        LDA(aB, t + 1);
        CELL(aA, t);
        LDA(aA, t + 2);                      // t+2 <= 48, always valid
        CELL(aB, t + 1);
    }
    CELL(aA, TPS - 1);                       // tile 48

    // decode + write candidates: [b][n][split][hi][4]
    int n = nt * 32 + lo;
    size_t base = (((size_t)(b * N_ + n) * SPLIT + split) * 2 + hi) * LCAP;
    float bs0 = b1, bs1 = b2, bs2 = b3, bs3 = b4;
    float bs[4] = {bs0, bs1, bs2, bs3};
    #pragma unroll
    for (int k = 0; k < 4; ++k) {
        u32 pb = __float_as_uint(bs[k]);
        int idx10 = (int)(pb & 1023u);
        int tl = idx10 >> 4, r = idx10 & 15;
        int m = (tbase + tl) * 32 + (r & 3) + ((r >> 2) << 3) + (hi << 2);
        cvals[base + k] = pb;
        cidx[base + k] = (u16)m;
    }
}

// ---------------------------------------------------------------------------
// Kernel 3: selective exact rescore. One wave per row, 1 candidate/lane.
// 3 wave-max rounds on noisy packed values -> t3; only lanes with
// vn >= t3 - 0.125 (noise+grain bound ~0.04, 3x margin; provably includes
// the true top-3) recompute the bit-identical round-1 fp32 dot. Exact
// selection (tie: lower index) + exact weights -> absmax 0 preserved.
// ---------------------------------------------------------------------------
__global__ __launch_bounds__(256)
void rescore(const u32* __restrict__ cvals, const u16* __restrict__ cidx,
             const float* __restrict__ fx, const float* __restrict__ fynT,
             const float* __restrict__ nyeps, const float* __restrict__ minf,
             const unsigned char* __restrict__ mask1b,
             const int* __restrict__ flags, float* __restrict__ out) {
    int gw = blockIdx.x * 4 + (threadIdx.x >> 6);    // row = b*N + n  (grid exact)
    int lane = threadIdx.x & 63;
    int b = gw / N_, n = gw - b * N_;

    float vn = __uint_as_float(cvals[(size_t)gw * CPR + lane]);
    int idx = cidx[(size_t)gw * CPR + lane];

    // 3rd-largest noisy value (equal values knock out together -> redo set
    // only grows; all 64 candidates are genuine, streams are full)
    float cur = vn;
    float t3 = NEGINF;
    #pragma unroll
    for (int r = 0; r < 3; ++r) {
        float c = cur;
        #pragma unroll
        for (int off = 32; off >= 1; off >>= 1) c = fmaxf(c, __shfl_xor(c, off));
        t3 = c;
        cur = (cur == c) ? NEGINF : cur;
    }
    bool redo = (vn >= t3 - 0.125f);

    float rnk = NEGINF, wgt = 0.f;
    if (redo) {
        const float* fxb = fx + (size_t)b * C_ * N_ + n;   // fx[b][c][n], stride N_
        const float4* fr4 = (const float4*)(fynT + ((size_t)b * N_ + idx) * C_);
        float a = 0.f;
        #pragma unroll
        for (int c4 = 0; c4 < 16; ++c4) {
            float4 f = fr4[c4];
            int c = c4 * 4;
            a = fmaf(fxb[(size_t)(c + 0) * N_], f.x, a);
            a = fmaf(fxb[(size_t)(c + 1) * N_], f.y, a);
            a = fmaf(fxb[(size_t)(c + 2) * N_], f.z, a);
            a = fmaf(fxb[(size_t)(c + 3) * N_], f.w, a);
        }
        rnk = a + minf[(size_t)b * N_ + idx];
        wgt = a * nyeps[(size_t)b * N_ + idx];
    }
    int midx = redo ? idx : 0x7fffffff;

    int wi[3]; float ww[3];
    #pragma unroll
    for (int r = 0; r < 3; ++r) {
        float cv = rnk; int ci = midx; float cw = wgt;
        #pragma unroll
        for (int off = 32; off >= 1; off >>= 1) {
            float ov = __shfl_xor(cv, off);
            int   oi = __shfl_xor(ci, off);
            float ow = __shfl_xor(cw, off);
            bool take = (ov > cv) || (ov == cv && oi < ci);
            cv = take ? ov : cv; ci = take ? oi : ci; cw = take ? ow : cw;
        }
        wi[r] = ci; ww[r] = cw;
        if (midx == ci) rnk = NEGINF;   // remove winner (and duplicates)
    }

    if (lane == 0) {
        float w0 = ww[0], w1 = ww[1], w2 = ww[2];
        float h0 = (float)(wi[0] / W_), h1 = (float)(wi[1] / W_), h2 = (float)(wi[2] / W_);
        float q0 = (float)(wi[0] % W_), q1 = (float)(wi[1] % W_), q2 = (float)(wi[2] % W_);
        float den = w0 + w1 + w2;
        float ph = (h0 * w0 + h1 * w1 + h2 * w2) / den;
        float pw = (q0 * w0 + q1 * w1 + q2 * w2) / den;
        bool m1 = flags[0] ? (mask1b[gw] != 0) : (((const int*)mask1b)[gw] != 0);
        out[2 * gw]     = m1 ? ph : -1.0f;
        out[2 * gw + 1] = m1 ? pw : -1.0f;
    }
}

// ---------------------------------------------------------------------------
// Kernel 4: slic gather.
// ---------------------------------------------------------------------------
__global__ void slic_gather(const float* __restrict__ spg,
                            const float* __restrict__ pred,
                            float* __restrict__ outg) {
    int t = blockIdx.x * blockDim.x + threadIdx.x;
    if (t >= B_ * S_ * G_) return;
    int b = t / (S_ * G_);
    float vh = spg[2 * t], vw = spg[2 * t + 1];
    int ph = (int)rintf(vh * (float)H_);
    int pw = (int)rintf(vw * (float)H_);
    ph = ph < 0 ? 0 : (ph > H_ - 1 ? H_ - 1 : ph);
    pw = pw < 0 ? 0 : (pw > H_ - 1 ? H_ - 1 : pw);
    int lin = ph * W_ + pw;
    outg[2 * t]     = pred[((size_t)b * N_ + lin) * 2]     / (float)H_;
    outg[2 * t + 1] = pred[((size_t)b * N_ + lin) * 2 + 1] / (float)H_;
}

extern "C" void kernel_launch(void* const* d_in, const int* in_sizes, int n_in,
                              void* d_out, int out_size, void* d_ws, size_t ws_size,
                              hipStream_t stream) {
    const float* img1 = (const float*)d_in[0];
    const float* img2 = (const float*)d_in[1];
    const void*  mask1 = d_in[2];
    const void*  mask2 = d_in[3];
    const float* spg = (const float*)d_in[4];
    float* out = (float*)d_out;

    char* ws = (char*)d_ws;
    size_t off = 0;
    int*   flags = (int*)(ws + off);            off += 256;
    float* fynT  = (float*)(ws + off);          off += (size_t)B_ * N_ * C_ * 4;       // 6.42 MB
    f16*   fxq   = (f16*)(ws + off);            off += (size_t)B_ * NT * KS * 64 * 16; // 4.01 MB
    f16*   fynq  = (f16*)(ws + off);            off += (size_t)B_ * MT * KS * 64 * 16; // 4.01 MB
    float* nyeps = (float*)(ws + off);          off += (size_t)B_ * N_ * 4;
    float* minf  = (float*)(ws + off);          off += (size_t)B_ * N_ * 4;
    u32*   cvals = (u32*)(ws + off);            off += (size_t)B_ * N_ * CPR * 4;      // 6.42 MB
    u16*   cidx  = (u16*)(ws + off);            off += (size_t)B_ * N_ * CPR * 2;      // 3.21 MB

    detect_fmt<<<1, 1024, 0, stream>>>((const u32*)mask1, (const u32*)mask2,
                                       (B_ * N_) / 4, flags);
    dim3 gp((B_ * N_) / 256, 2);
    prep<<<gp, 256, 0, stream>>>(img1, img2, (const unsigned char*)mask2, flags,
                                 fxq, fynT, fynq, nyeps, minf);

    dim3 g1(98, SPLIT, B_);
    stage1<<<g1, 256, 0, stream>>>(fxq, fynq, cvals, cidx);

    rescore<<<(B_ * N_) / 4, 256, 0, stream>>>(
        cvals, cidx, img1, fynT, nyeps, minf,
        (const unsigned char*)mask1, flags, out);

    slic_gather<<<(B_ * S_ * G_ + 255) / 256, 256, 0, stream>>>(
        spg, out, out + (size_t)B_ * N_ * 2);
}